// Round 12
// baseline (195.866 us; speedup 1.0000x reference)
//
#include <hip/hip_runtime.h>
#include <math.h>

#define EPSF 1e-6f

typedef __attribute__((ext_vector_type(8))) short bf16x8;
typedef __attribute__((ext_vector_type(4))) float f32x4;
typedef unsigned short u16;
typedef unsigned int u32;

#define MFMA16(a,b,c) __builtin_amdgcn_mfma_f32_16x16x32_bf16((a),(b),(c),0,0,0)

__device__ __forceinline__ u16 f2bf(float f){
  u32 x = __builtin_bit_cast(u32, f);
  u32 r = (x + 0x7fffu + ((x >> 16) & 1u)) >> 16;
  return (u16)r;
}
__device__ __forceinline__ void gll16(const void* g, void* l){
  __builtin_amdgcn_global_load_lds(
      (const __attribute__((address_space(1))) u32*)g,
      (__attribute__((address_space(3))) u32*)l, 16, 0, 0);
}

// ---------------- k0: pack weights to bf16 ---------------------------------
__global__ __launch_bounds__(256) void k0_prep(
    const float* __restrict__ wq, const float* __restrict__ bq,
    const float* __restrict__ wk, const float* __restrict__ bk,
    const float* __restrict__ wv, const float* __restrict__ bv,
    const float* __restrict__ wg, const float* __restrict__ bg,
    const float* __restrict__ pw_w, const float* __restrict__ wo,
    u16* __restrict__ wpack, u16* __restrict__ pwb, u16* __restrict__ wob,
    float* __restrict__ bpack)
{
  int idx = blockIdx.x*256 + threadIdx.x;
  const int NW = 1536*384;
  if (idx < NW) {
    int r = idx / 384, c = idx - r*384;
    int h = r / 192, s = (r % 192)/48, d = r % 48;
    const float* w = (s==0)?wq:(s==1)?wk:(s==2)?wv:wg;
    wpack[idx] = f2bf(w[(h*48+d)*384 + c]);
    if (c==0){
      const float* b = (s==0)?bq:(s==1)?bk:(s==2)?bv:bg;
      bpack[r] = b[h*48+d];
    }
  } else if (idx < NW + 147456) {
    pwb[idx - NW] = f2bf(pw_w[idx - NW]);
  } else if (idx < NW + 2*147456) {
    wob[idx - NW - 147456] = f2bf(wo[idx - NW - 147456]);
  }
}

// ---------------- k1: depthwise 3x3 conv (+dw_b) -> t bf16 ----------------
__global__ __launch_bounds__(256) void k1_dw(
    const float* __restrict__ x, const float* __restrict__ dw_w,
    const float* __restrict__ dw_b, u16* __restrict__ t)
{
  int idx = blockIdx.x*256 + threadIdx.x;   // 786432 threads
  int c4 = idx % 96; int rest = idx / 96;
  int jg = rest & 15; rest >>= 4;
  int i = rest & 63; int b = rest >> 6;
  int c0 = c4*4, j0 = jg*4;
  float wf[36];
  {
    const float4* wp = (const float4*)(dw_w + c0*9);
    #pragma unroll
    for (int k=0;k<9;k++){
      float4 v = wp[k];
      wf[4*k] = v.x; wf[4*k+1] = v.y; wf[4*k+2] = v.z; wf[4*k+3] = v.w;
    }
  }
  float4 bias = *(const float4*)(dw_b + c0);
  float acc[4][4];
  #pragma unroll
  for (int tk=0;tk<4;tk++){
    acc[tk][0]=bias.x; acc[tk][1]=bias.y; acc[tk][2]=bias.z; acc[tk][3]=bias.w;
  }
  const float* xb = x + ((size_t)b<<12)*384;
  #pragma unroll
  for (int di=-1; di<=1; ++di){
    int ii = i+di; if ((unsigned)ii >= 64u) continue;
    #pragma unroll
    for (int dj=-1; dj<=4; ++dj){
      int jj = j0+dj; if ((unsigned)jj >= 64u) continue;
      float4 xv = *(const float4*)(xb + (size_t)((ii<<6)+jj)*384 + c0);
      #pragma unroll
      for (int tk=0;tk<4;tk++){
        const int dd = dj - tk;
        if (dd < -1 || dd > 1) continue;
        const int tap = (di+1)*3 + (dd+1);
        acc[tk][0] = fmaf(xv.x, wf[0*9+tap], acc[tk][0]);
        acc[tk][1] = fmaf(xv.y, wf[1*9+tap], acc[tk][1]);
        acc[tk][2] = fmaf(xv.z, wf[2*9+tap], acc[tk][2]);
        acc[tk][3] = fmaf(xv.w, wf[3*9+tap], acc[tk][3]);
      }
    }
  }
  int mbase = (b<<12) + (i<<6) + j0;
  #pragma unroll
  for (int tk=0;tk<4;tk++){
    ushort4 o; o.x=f2bf(acc[tk][0]); o.y=f2bf(acc[tk][1]);
    o.z=f2bf(acc[tk][2]); o.w=f2bf(acc[tk][3]);
    *(ushort4*)(t + (size_t)(mbase+tk)*384 + c0) = o;
  }
}

// ---------------- k2: xm = bf16( x + t @ pw^T + pw_b ), dbuf prefetch -----
__global__ __launch_bounds__(256) void k2_gemm_pw(
    const u16* __restrict__ t, const u16* __restrict__ pwb,
    const float* __restrict__ x, const float* __restrict__ pw_b,
    u16* __restrict__ xm)
{
  __shared__ __align__(16) u16 smem[32768];  // 64KB: A dbuf 2x16KB, B dbuf 2x16KB
  const int m0 = blockIdx.x * 128;
  const int n0 = blockIdx.y * 128;
  const int tid = threadIdx.x, w = tid>>6, l = tid&63;
  const int lc = l & 15, hi = l >> 4;
  const int osw = ((l&7) ^ (l>>3))*16;
  const f32x4 zf = {0.f,0.f,0.f,0.f};
  f32x4 acc[4][4];
  #pragma unroll
  for (int i=0;i<4;i++)
    #pragma unroll
    for (int j=0;j<4;j++) acc[i][j] = zf;

  const int srow = (w*4)*8 + (l>>3);

  #define K2_STAGE(T, BUF) do {                                            \
    const int k0_ = (T)*64;                                                \
    char* Ab_ = (char*)(smem + (BUF)*8192);                                \
    char* Bb_ = (char*)(smem + 16384 + (BUF)*8192);                        \
    _Pragma("unroll")                                                      \
    for (int i=0;i<4;i++){                                                 \
      gll16((const char*)t   + ((size_t)(m0+srow+i*8)*384 + k0_)*2 + osw,  \
            Ab_ + (w*4+i)*1024);                                           \
      gll16((const char*)pwb + ((size_t)(n0+srow+i*8)*384 + k0_)*2 + osw,  \
            Bb_ + (w*4+i)*1024);                                           \
    }                                                                      \
  } while(0)

  K2_STAGE(0, 0);
  __syncthreads();
  int cur = 0;
  for (int t_=0; t_<6; ++t_){
    if (t_ < 5) K2_STAGE(t_+1, cur^1);
    const u16* As = smem + cur*8192;
    const u16* Bs = smem + 16384 + cur*8192;
    const int wr = (w>>1)*64, wc = (w&1)*64;
    #pragma unroll
    for (int kk=0; kk<64; kk+=32){
      const int sc = (((kk>>3)+hi) ^ (lc&7))*8;
      bf16x8 a[4], bb[4];
      #pragma unroll
      for (int i=0;i<4;i++) a[i]  = *(const bf16x8*)&As[(wr + i*16 + lc)*64 + sc];
      #pragma unroll
      for (int j=0;j<4;j++) bb[j] = *(const bf16x8*)&Bs[(wc + j*16 + lc)*64 + sc];
      #pragma unroll
      for (int i=0;i<4;i++)
        #pragma unroll
        for (int j=0;j<4;j++)
          acc[i][j] = MFMA16(a[i], bb[j], acc[i][j]);
    }
    __syncthreads();
    cur ^= 1;
  }
  #undef K2_STAGE
  const int wr=(w>>1)*64, wc=(w&1)*64;
  #pragma unroll
  for (int j=0;j<4;j++){
    int n = n0 + wc + j*16 + lc;
    float bias = pw_b[n];
    #pragma unroll
    for (int i=0;i<4;i++)
      #pragma unroll
      for (int r=0;r<4;r++){
        int m = m0 + wr + i*16 + hi*4 + r;
        float v = acc[i][j][r] + x[(size_t)m*384 + n] + bias;
        xm[(size_t)m*384 + n] = f2bf(v);
      }
  }
}

// ---------------- k3: fused QKVG GEMM (R10 version, reverted) -------------
__global__ __launch_bounds__(256) void k3_gemm_qkvg(
    const u16* __restrict__ xm, const u16* __restrict__ wpack,
    const float* __restrict__ bpack, const float* __restrict__ temperature,
    u16* __restrict__ qh, float* __restrict__ pkv, float* __restrict__ pks)
{
  __shared__ __align__(16) u16 smem[40960];   // 80KB
  const int m0 = blockIdx.x * 128;
  const int h  = blockIdx.y;
  const int tid = threadIdx.x, w = tid>>6, l = tid&63;
  const int lc = l & 15, hi = l >> 4;
  const int osw = ((l&7) ^ (l>>3))*16;
  const f32x4 zf = {0.f,0.f,0.f,0.f};
  f32x4 acc[2][12];
  #pragma unroll
  for (int i=0;i<2;i++)
    #pragma unroll
    for (int j=0;j<12;j++) acc[i][j] = zf;

  const int arow = (w*4)*8 + (l>>3);
  const int brow = (w*6)*8 + (l>>3);

  #define K3_STAGE(T, BUF) do {                                                \
    const int k0_ = (T)*64;                                                    \
    char* Ab_ = (char*)(smem + (BUF)*8192);                                    \
    char* Bb_ = (char*)(smem + 16384 + (BUF)*12288);                           \
    _Pragma("unroll")                                                          \
    for (int i=0;i<4;i++)                                                      \
      gll16((const char*)xm + ((size_t)(m0+arow+i*8)*384 + k0_)*2 + osw,       \
            Ab_ + (w*4+i)*1024);                                               \
    _Pragma("unroll")                                                          \
    for (int i=0;i<6;i++)                                                      \
      gll16((const char*)wpack + ((size_t)(h*192+brow+i*8)*384 + k0_)*2 + osw, \
            Bb_ + (w*6+i)*1024);                                               \
  } while(0)

  K3_STAGE(0, 0);
  __syncthreads();
  int cur = 0;
  const int rbase = w*32;
  for (int t=0; t<6; ++t){
    if (t < 5) K3_STAGE(t+1, cur^1);
    const u16* Ab = smem + cur*8192;
    const u16* Bb = smem + 16384 + cur*12288;
    #pragma unroll
    for (int kk=0; kk<64; kk+=32){
      const int sc = (((kk>>3)+hi) ^ (lc&7))*8;
      bf16x8 a0 = *(const bf16x8*)&Ab[(rbase +      lc)*64 + sc];
      bf16x8 a1 = *(const bf16x8*)&Ab[(rbase + 16 + lc)*64 + sc];
      #pragma unroll
      for (int j=0;j<12;j++){
        bf16x8 bb = *(const bf16x8*)&Bb[(j*16 + lc)*64 + sc];
        acc[0][j] = MFMA16(a0, bb, acc[0][j]);
        acc[1][j] = MFMA16(a1, bb, acc[1][j]);
      }
    }
    __syncthreads();
    cur ^= 1;
  }
  #undef K3_STAGE

  // ---- epilogue (fast-math transcendentals) ----
  const float tq = temperature[h];
  const int b = m0 >> 12;
  const int mtile = (m0 >> 7) & 31;
  const size_t bh = (size_t)b*8 + h;
  const int bb0 = h*192;
  float biasq[3], biask[3], biasv[3], biasg[3];
  #pragma unroll
  for (int j=0;j<3;j++){
    biasq[j] = bpack[bb0       + j*16 + lc];
    biask[j] = bpack[bb0 + 48  + j*16 + lc];
    biasv[j] = bpack[bb0 + 96  + j*16 + lc];
    biasg[j] = bpack[bb0 + 144 + j*16 + lc];
  }
  u16* kT = smem;          // [48][136]
  u16* vT = smem + 6528;   // [48][136]
  float ksp[3] = {0.f, 0.f, 0.f};

  #pragma unroll
  for (int i=0;i<2;i++){
    ushort4 kst[3], vst[3];
    #pragma unroll
    for (int r=0;r<4;r++){
      int m = m0 + w*32 + i*16 + hi*4 + r;
      int n = m & 4095;
      size_t rowq = (bh*4096 + n)*48;
      float q0=(acc[i][0][r]+biasq[0])*tq;
      float q1=(acc[i][1][r]+biasq[1])*tq;
      float q2=(acc[i][2][r]+biasq[2])*tq;
      qh[rowq +      lc] = f2bf(__expf(q0));
      qh[rowq + 16 + lc] = f2bf(__expf(q1));
      qh[rowq + 32 + lc] = f2bf(__expf(q2));
      float s0=acc[i][3][r]+biask[0];
      float s1=acc[i][4][r]+biask[1];
      float s2=acc[i][5][r]+biask[2];
      float mk = fmaxf(s0,fmaxf(s1,s2));
      mk = fmaxf(mk, __shfl_xor(mk,1,64));
      mk = fmaxf(mk, __shfl_xor(mk,2,64));
      mk = fmaxf(mk, __shfl_xor(mk,4,64));
      mk = fmaxf(mk, __shfl_xor(mk,8,64));
      float k0e = __expf(s0-mk), k1e = __expf(s1-mk), k2e = __expf(s2-mk);
      ksp[0] += k0e; ksp[1] += k1e; ksp[2] += k2e;
      u16 kq0=f2bf(k0e), kq1=f2bf(k1e), kq2=f2bf(k2e);
      u16 vq[3];
      #pragma unroll
      for (int j=0;j<3;j++){
        float vv = acc[i][6+j][r] + biasv[j];
        float gg = acc[i][9+j][r] + biasg[j];
        float sg = __builtin_amdgcn_rcpf(1.f + __expf(-gg));
        vq[j] = f2bf(vv*sg);
      }
      if (r==0){ kst[0].x=kq0; kst[1].x=kq1; kst[2].x=kq2; vst[0].x=vq[0]; vst[1].x=vq[1]; vst[2].x=vq[2]; }
      if (r==1){ kst[0].y=kq0; kst[1].y=kq1; kst[2].y=kq2; vst[0].y=vq[0]; vst[1].y=vq[1]; vst[2].y=vq[2]; }
      if (r==2){ kst[0].z=kq0; kst[1].z=kq1; kst[2].z=kq2; vst[0].z=vq[0]; vst[1].z=vq[1]; vst[2].z=vq[2]; }
      if (r==3){ kst[0].w=kq0; kst[1].w=kq1; kst[2].w=kq2; vst[0].w=vq[0]; vst[1].w=vq[1]; vst[2].w=vq[2]; }
    }
    int mb = w*32 + i*16 + hi*4;
    #pragma unroll
    for (int j=0;j<3;j++){
      *(ushort4*)&kT[(j*16+lc)*136 + mb] = kst[j];
      *(ushort4*)&vT[(j*16+lc)*136 + mb] = vst[j];
    }
  }
  __syncthreads();

  bf16x8 af[3], bfv[3];
  #pragma unroll
  for (int da=0;da<3;da++) af[da]  = *(const bf16x8*)&kT[(da*16+lc)*136 + w*32 + hi*8];
  #pragma unroll
  for (int eb=0;eb<3;eb++) bfv[eb] = *(const bf16x8*)&vT[(eb*16+lc)*136 + w*32 + hi*8];
  f32x4 a2[3][3];
  #pragma unroll
  for (int da=0;da<3;da++)
    #pragma unroll
    for (int eb=0;eb<3;eb++)
      a2[da][eb] = MFMA16(af[da], bfv[eb], zf);
  __syncthreads();
  float* pb = (float*)smem + w*2304;
  #pragma unroll
  for (int da=0;da<3;da++)
    #pragma unroll
    for (int eb=0;eb<3;eb++)
      #pragma unroll
      for (int rr=0;rr<4;rr++)
        pb[(da*16 + hi*4 + rr)*48 + eb*16 + lc] = a2[da][eb][rr];
  __syncthreads();
  {
    float* p0 = (float*)smem;
    float* dst = pkv + ((size_t)bh*32 + mtile)*2304;
    for (int u=tid; u<2304; u+=256)
      dst[u] = p0[u] + p0[2304+u] + p0[4608+u] + p0[6912+u];
  }
  #pragma unroll
  for (int j=0;j<3;j++){
    ksp[j] += __shfl_xor(ksp[j],16,64);
    ksp[j] += __shfl_xor(ksp[j],32,64);
  }
  __syncthreads();
  {
    float* kr = (float*)smem;           // [4][48]
    if (hi==0){ kr[w*48+lc]=ksp[0]; kr[w*48+16+lc]=ksp[1]; kr[w*48+32+lc]=ksp[2]; }
    __syncthreads();
    if (tid < 48){
      float* ds = pks + ((size_t)bh*32 + mtile)*48;
      ds[tid] = kr[tid] + kr[48+tid] + kr[96+tid] + kr[144+tid];
    }
  }
}

// ---------------- k5: reduce partials -> kvp[e][d] bf16 (64x64, ksum row48)
__global__ __launch_bounds__(256) void k5_red(
    const float* __restrict__ pkv, const float* __restrict__ pks,
    u16* __restrict__ kvp)
{
  __shared__ float sm[2304];
  __shared__ float ks[48];
  int bh = blockIdx.x, tid = threadIdx.x;
  const float* base = pkv + (size_t)bh*32*2304;
  for (int u=tid; u<2304; u+=256){
    float v = 0.f;
    #pragma unroll
    for (int m=0;m<32;m++) v += base[(size_t)m*2304 + u];
    sm[u] = v;
  }
  if (tid < 48){
    const float* bk = pks + (size_t)bh*32*48 + tid;
    float v = 0.f;
    #pragma unroll
    for (int m=0;m<32;m++) v += bk[m*48];
    ks[tid] = v;
  }
  __syncthreads();
  for (int u=tid; u<4096; u+=256){
    int e = u >> 6, d = u & 63;
    float v = 0.f;
    if (e < 48 && d < 48)       v = sm[d*48 + e];
    else if (e == 48 && d < 48) v = ks[d];
    kvp[((size_t)bh*64 + e)*64 + d] = f2bf(v);
  }
}

// ---------------- k67: fused num/den + output GEMM -------------------------
// Per block (128 tokens x 128 out-ch): loop h=0..7:
//   stage qh-tile/kvp_h/wo_h -> MFMA1 (num,den) -> ahat bf16 in LDS ->
//   MFMA2 accumulates ahat @ wo_h^T. The ah intermediate never hits HBM.
__global__ __launch_bounds__(256) void k67_fused(
    const u16* __restrict__ qh, const u16* __restrict__ kvp,
    const u16* __restrict__ wob, const float* __restrict__ bo,
    float* __restrict__ out)
{
  __shared__ __align__(16) u16 q_lds[128*64];   // 16KB
  __shared__ __align__(16) u16 kv_lds[64*64];   //  8KB
  __shared__ __align__(16) u16 ah_lds[128*64];  // 16KB
  __shared__ __align__(16) u16 wo_lds[128*64];  // 16KB
  const int m0 = blockIdx.x * 128;
  const int n0 = blockIdx.y * 128;
  const int tid = threadIdx.x, w = tid>>6, l = tid&63;
  const int lc = l & 15, hi = l >> 4;
  const f32x4 zf = {0.f,0.f,0.f,0.f};
  const uint4 z4 = {0,0,0,0};
  const int b = m0 >> 12;
  const int nbase = m0 & 4095;

  // zero ah_lds once: pad chunk slots stay zero across all heads
  #pragma unroll
  for (int it=0; it<4; ++it) ((uint4*)ah_lds)[it*256 + tid] = z4;

  f32x4 acc_o[4][4];
  #pragma unroll
  for (int i=0;i<4;i++)
    #pragma unroll
    for (int j=0;j<4;j++) acc_o[i][j] = zf;

  for (int h = 0; h < 8; ++h){
    const size_t bh = (size_t)b*8 + h;
    // ---- stage q [128][64], kvp [64][64], wo [128][64] (chunk-XOR) ----
    {
      const u16* gq = qh + (bh*4096 + (size_t)nbase)*48;
      #pragma unroll
      for (int it=0; it<4; ++it){
        int s = it*256 + tid;
        int row = s>>3, c = s&7, g = c ^ (row&7);
        ((uint4*)q_lds)[s] = (g < 6) ? *(const uint4*)(gq + (size_t)row*48 + g*8) : z4;
      }
      const u16* gk = kvp + bh*4096;
      #pragma unroll
      for (int it=0; it<2; ++it){
        int s = it*256 + tid;
        int row = s>>3, c = s&7, g = c ^ (row&7);
        ((uint4*)kv_lds)[s] = *(const uint4*)(gk + (size_t)row*64 + g*8);
      }
      const u16* gw = wob + (size_t)n0*384 + h*48;
      #pragma unroll
      for (int it=0; it<4; ++it){
        int s = it*256 + tid;
        int row = s>>3, c = s&7, g = c ^ (row&7);
        ((uint4*)wo_lds)[s] = (g < 6) ? *(const uint4*)(gw + (size_t)row*384 + g*8) : z4;
      }
    }
    __syncthreads();

    // ---- MFMA1: num/den for wave's 32 tokens ----
    f32x4 aq[2][4];
    #pragma unroll
    for (int i=0;i<2;i++)
      #pragma unroll
      for (int j=0;j<4;j++) aq[i][j] = zf;
    #pragma unroll
    for (int kk=0; kk<64; kk+=32){
      const int sc = (((kk>>3)+hi) ^ (lc&7))*8;
      bf16x8 a0 = *(const bf16x8*)&q_lds[(w*32 +      lc)*64 + sc];
      bf16x8 a1 = *(const bf16x8*)&q_lds[(w*32 + 16 + lc)*64 + sc];
      bf16x8 bb[4];
      #pragma unroll
      for (int j=0;j<4;j++) bb[j] = *(const bf16x8*)&kv_lds[(j*16 + lc)*64 + sc];
      #pragma unroll
      for (int j=0;j<4;j++){
        aq[0][j] = MFMA16(a0, bb[j], aq[0][j]);
        aq[1][j] = MFMA16(a1, bb[j], aq[1][j]);
      }
    }
    // normalize and write ahat (swizzle-consistent scalar writes)
    #pragma unroll
    for (int i=0;i<2;i++){
      #pragma unroll
      for (int r=0;r<4;r++){
        float den = __shfl(aq[i][3][r], l & 48, 64) + EPSF;
        float rd = __builtin_amdgcn_rcpf(den);
        int tr = w*32 + i*16 + hi*4 + r;
        #pragma unroll
        for (int j=0;j<3;j++){
          int e = j*16 + lc;
          int cslot = ((e>>3) ^ (tr&7))*8 + (e&7);
          ah_lds[tr*64 + cslot] = f2bf(aq[i][j][r]*rd);
        }
      }
    }
    __syncthreads();

    // ---- MFMA2: acc_o += ahat @ wo_h^T (K=64, cols 48..63 zero) ----
    const int wr = (w>>1)*64, wc = (w&1)*64;
    #pragma unroll
    for (int kk=0; kk<64; kk+=32){
      const int sc = (((kk>>3)+hi) ^ (lc&7))*8;
      bf16x8 a[4], bb[4];
      #pragma unroll
      for (int i=0;i<4;i++) a[i]  = *(const bf16x8*)&ah_lds[(wr + i*16 + lc)*64 + sc];
      #pragma unroll
      for (int j=0;j<4;j++) bb[j] = *(const bf16x8*)&wo_lds[(wc + j*16 + lc)*64 + sc];
      #pragma unroll
      for (int i=0;i<4;i++)
        #pragma unroll
        for (int j=0;j<4;j++)
          acc_o[i][j] = MFMA16(a[i], bb[j], acc_o[i][j]);
    }
    __syncthreads();
  }

  // ---- epilogue: out = acc_o + bo ----
  const int wr=(w>>1)*64, wc=(w&1)*64;
  #pragma unroll
  for (int j=0;j<4;j++){
    int n = n0 + wc + j*16 + lc;
    float bias = bo[n];
    #pragma unroll
    for (int i=0;i<4;i++)
      #pragma unroll
      for (int r=0;r<4;r++){
        int m = m0 + wr + i*16 + hi*4 + r;
        out[(size_t)m*384 + n] = acc_o[i][j][r] + bias;
      }
  }
}

extern "C" void kernel_launch(void* const* d_in, const int* in_sizes, int n_in,
                              void* d_out, int out_size, void* d_ws, size_t ws_size,
                              hipStream_t stream)
{
  const float* x    = (const float*)d_in[0];
  const float* wq   = (const float*)d_in[1];
  const float* bq   = (const float*)d_in[2];
  const float* wk   = (const float*)d_in[3];
  const float* bk   = (const float*)d_in[4];
  const float* wv   = (const float*)d_in[5];
  const float* bv   = (const float*)d_in[6];
  const float* wg   = (const float*)d_in[7];
  const float* bg   = (const float*)d_in[8];
  const float* wo   = (const float*)d_in[9];
  const float* bo   = (const float*)d_in[10];
  const float* temp = (const float*)d_in[11];
  const float* dw_w = (const float*)d_in[12];
  const float* dw_b = (const float*)d_in[13];
  const float* pw_w = (const float*)d_in[14];
  const float* pw_b = (const float*)d_in[15];
  float* out = (float*)d_out;
  char* ws = (char*)d_ws;

  u16*   t       = (u16*)(ws + 0);
  float* pkv     = (float*)(ws + 0);          // 18874368  [64][32][2304] f32
  float* pks     = (float*)(ws + 18874368);   // 393216    [64][32][48] f32
  u16*   xm      = (u16*)(ws + 25165824);     // 25165824
  u16*   qh      = (u16*)(ws + 50331648);     // 25165824  [B,H,N,48]
  u16*   wpack   = (u16*)(ws + 83886080);     // 1179648
  u16*   pwb     = (u16*)(ws + 85065728);     // 294912
  u16*   wob     = (u16*)(ws + 85360640);     // 294912
  float* bpack   = (float*)(ws + 85655552);   // 6144
  u16*   kvp     = (u16*)(ws + 85661696);     // 524288  [64][64][64] bf16

  k0_prep<<<3456, 256, 0, stream>>>(wq,bq,wk,bk,wv,bv,wg,bg,pw_w,wo,
                                    wpack,pwb,wob,bpack);
  k1_dw<<<3072, 256, 0, stream>>>(x, dw_w, dw_b, t);
  k2_gemm_pw<<<dim3(256,3), 256, 0, stream>>>(t, pwb, x, pw_b, xm);
  k3_gemm_qkvg<<<dim3(256,8), 256, 0, stream>>>(xm, wpack, bpack, temp, qh, pkv, pks);
  k5_red<<<64, 256, 0, stream>>>(pkv, pks, kvp);
  k67_fused<<<dim3(256,3), 256, 0, stream>>>(qh, kvp, wob, bo, out);
}

// Round 13
// 174.441 us; speedup vs baseline: 1.1228x; 1.1228x over previous
//
#include <hip/hip_runtime.h>
#include <math.h>

#define EPSF 1e-6f

typedef __attribute__((ext_vector_type(8))) short bf16x8;
typedef __attribute__((ext_vector_type(4))) float f32x4;
typedef unsigned short u16;
typedef unsigned int u32;

#define MFMA16(a,b,c) __builtin_amdgcn_mfma_f32_16x16x32_bf16((a),(b),(c),0,0,0)

__device__ __forceinline__ u16 f2bf(float f){
  u32 x = __builtin_bit_cast(u32, f);
  u32 r = (x + 0x7fffu + ((x >> 16) & 1u)) >> 16;
  return (u16)r;
}
__device__ __forceinline__ void gll16(const void* g, void* l){
  __builtin_amdgcn_global_load_lds(
      (const __attribute__((address_space(1))) u32*)g,
      (__attribute__((address_space(3))) u32*)l, 16, 0, 0);
}

// ---------------- k01: weight pack (blocks 0..3455) + dw conv (3456..6527)
__global__ __launch_bounds__(256) void k01_prep_dw(
    const float* __restrict__ wq, const float* __restrict__ bq,
    const float* __restrict__ wk, const float* __restrict__ bk,
    const float* __restrict__ wv, const float* __restrict__ bv,
    const float* __restrict__ wg, const float* __restrict__ bg,
    const float* __restrict__ pw_w, const float* __restrict__ wo,
    u16* __restrict__ wpack, u16* __restrict__ pwb, u16* __restrict__ wob,
    float* __restrict__ bpack,
    const float* __restrict__ x, const float* __restrict__ dw_w,
    const float* __restrict__ dw_b, u16* __restrict__ t)
{
  if (blockIdx.x < 3456){
    int idx = blockIdx.x*256 + threadIdx.x;
    const int NW = 1536*384;
    if (idx < NW) {
      int r = idx / 384, c = idx - r*384;
      int h = r / 192, s = (r % 192)/48, d = r % 48;
      const float* w = (s==0)?wq:(s==1)?wk:(s==2)?wv:wg;
      wpack[idx] = f2bf(w[(h*48+d)*384 + c]);
      if (c==0){
        const float* b = (s==0)?bq:(s==1)?bk:(s==2)?bv:bg;
        bpack[r] = b[h*48+d];
      }
    } else if (idx < NW + 147456) {
      pwb[idx - NW] = f2bf(pw_w[idx - NW]);
    } else if (idx < NW + 2*147456) {
      wob[idx - NW - 147456] = f2bf(wo[idx - NW - 147456]);
    }
    return;
  }
  int idx = (blockIdx.x - 3456)*256 + threadIdx.x;   // 786432 threads
  int c4 = idx % 96; int rest = idx / 96;
  int jg = rest & 15; rest >>= 4;
  int i = rest & 63; int b = rest >> 6;
  int c0 = c4*4, j0 = jg*4;
  float wf[36];
  {
    const float4* wp = (const float4*)(dw_w + c0*9);
    #pragma unroll
    for (int k=0;k<9;k++){
      float4 v = wp[k];
      wf[4*k] = v.x; wf[4*k+1] = v.y; wf[4*k+2] = v.z; wf[4*k+3] = v.w;
    }
  }
  float4 bias = *(const float4*)(dw_b + c0);
  float acc[4][4];
  #pragma unroll
  for (int tk=0;tk<4;tk++){
    acc[tk][0]=bias.x; acc[tk][1]=bias.y; acc[tk][2]=bias.z; acc[tk][3]=bias.w;
  }
  const float* xb = x + ((size_t)b<<12)*384;
  #pragma unroll
  for (int di=-1; di<=1; ++di){
    int ii = i+di; if ((unsigned)ii >= 64u) continue;
    #pragma unroll
    for (int dj=-1; dj<=4; ++dj){
      int jj = j0+dj; if ((unsigned)jj >= 64u) continue;
      float4 xv = *(const float4*)(xb + (size_t)((ii<<6)+jj)*384 + c0);
      #pragma unroll
      for (int tk=0;tk<4;tk++){
        const int dd = dj - tk;
        if (dd < -1 || dd > 1) continue;
        const int tap = (di+1)*3 + (dd+1);
        acc[tk][0] = fmaf(xv.x, wf[0*9+tap], acc[tk][0]);
        acc[tk][1] = fmaf(xv.y, wf[1*9+tap], acc[tk][1]);
        acc[tk][2] = fmaf(xv.z, wf[2*9+tap], acc[tk][2]);
        acc[tk][3] = fmaf(xv.w, wf[3*9+tap], acc[tk][3]);
      }
    }
  }
  int mbase = (b<<12) + (i<<6) + j0;
  #pragma unroll
  for (int tk=0;tk<4;tk++){
    ushort4 o; o.x=f2bf(acc[tk][0]); o.y=f2bf(acc[tk][1]);
    o.z=f2bf(acc[tk][2]); o.w=f2bf(acc[tk][3]);
    *(ushort4*)(t + (size_t)(mbase+tk)*384 + c0) = o;
  }
}

// ---------------- k2: xm = bf16( x + t @ pw^T + pw_b ), dbuf prefetch -----
__global__ __launch_bounds__(256) void k2_gemm_pw(
    const u16* __restrict__ t, const u16* __restrict__ pwb,
    const float* __restrict__ x, const float* __restrict__ pw_b,
    u16* __restrict__ xm)
{
  __shared__ __align__(16) u16 smem[32768];  // 64KB: A dbuf 2x16KB, B dbuf 2x16KB
  const int m0 = blockIdx.x * 128;
  const int n0 = blockIdx.y * 128;
  const int tid = threadIdx.x, w = tid>>6, l = tid&63;
  const int lc = l & 15, hi = l >> 4;
  const int osw = ((l&7) ^ (l>>3))*16;
  const f32x4 zf = {0.f,0.f,0.f,0.f};
  f32x4 acc[4][4];
  #pragma unroll
  for (int i=0;i<4;i++)
    #pragma unroll
    for (int j=0;j<4;j++) acc[i][j] = zf;

  const int srow = (w*4)*8 + (l>>3);

  #define K2_STAGE(T, BUF) do {                                            \
    const int k0_ = (T)*64;                                                \
    char* Ab_ = (char*)(smem + (BUF)*8192);                                \
    char* Bb_ = (char*)(smem + 16384 + (BUF)*8192);                        \
    _Pragma("unroll")                                                      \
    for (int i=0;i<4;i++){                                                 \
      gll16((const char*)t   + ((size_t)(m0+srow+i*8)*384 + k0_)*2 + osw,  \
            Ab_ + (w*4+i)*1024);                                           \
      gll16((const char*)pwb + ((size_t)(n0+srow+i*8)*384 + k0_)*2 + osw,  \
            Bb_ + (w*4+i)*1024);                                           \
    }                                                                      \
  } while(0)

  K2_STAGE(0, 0);
  __syncthreads();
  int cur = 0;
  for (int t_=0; t_<6; ++t_){
    if (t_ < 5) K2_STAGE(t_+1, cur^1);
    const u16* As = smem + cur*8192;
    const u16* Bs = smem + 16384 + cur*8192;
    const int wr = (w>>1)*64, wc = (w&1)*64;
    #pragma unroll
    for (int kk=0; kk<64; kk+=32){
      const int sc = (((kk>>3)+hi) ^ (lc&7))*8;
      bf16x8 a[4], bb[4];
      #pragma unroll
      for (int i=0;i<4;i++) a[i]  = *(const bf16x8*)&As[(wr + i*16 + lc)*64 + sc];
      #pragma unroll
      for (int j=0;j<4;j++) bb[j] = *(const bf16x8*)&Bs[(wc + j*16 + lc)*64 + sc];
      #pragma unroll
      for (int i=0;i<4;i++)
        #pragma unroll
        for (int j=0;j<4;j++)
          acc[i][j] = MFMA16(a[i], bb[j], acc[i][j]);
    }
    __syncthreads();
    cur ^= 1;
  }
  #undef K2_STAGE
  const int wr=(w>>1)*64, wc=(w&1)*64;
  #pragma unroll
  for (int j=0;j<4;j++){
    int n = n0 + wc + j*16 + lc;
    float bias = pw_b[n];
    #pragma unroll
    for (int i=0;i<4;i++)
      #pragma unroll
      for (int r=0;r<4;r++){
        int m = m0 + wr + i*16 + hi*4 + r;
        float v = acc[i][j][r] + x[(size_t)m*384 + n] + bias;
        xm[(size_t)m*384 + n] = f2bf(v);
      }
  }
}

// ---------------- k3: fused QKVG GEMM (R10 version; grid (8,256) for L2) --
__global__ __launch_bounds__(256) void k3_gemm_qkvg(
    const u16* __restrict__ xm, const u16* __restrict__ wpack,
    const float* __restrict__ bpack, const float* __restrict__ temperature,
    u16* __restrict__ qh, float* __restrict__ pkv, float* __restrict__ pks)
{
  __shared__ __align__(16) u16 smem[40960];   // 80KB
  const int m0 = blockIdx.y * 128;
  const int h  = blockIdx.x;
  const int tid = threadIdx.x, w = tid>>6, l = tid&63;
  const int lc = l & 15, hi = l >> 4;
  const int osw = ((l&7) ^ (l>>3))*16;
  const f32x4 zf = {0.f,0.f,0.f,0.f};
  f32x4 acc[2][12];
  #pragma unroll
  for (int i=0;i<2;i++)
    #pragma unroll
    for (int j=0;j<12;j++) acc[i][j] = zf;

  const int arow = (w*4)*8 + (l>>3);
  const int brow = (w*6)*8 + (l>>3);

  #define K3_STAGE(T, BUF) do {                                                \
    const int k0_ = (T)*64;                                                    \
    char* Ab_ = (char*)(smem + (BUF)*8192);                                    \
    char* Bb_ = (char*)(smem + 16384 + (BUF)*12288);                           \
    _Pragma("unroll")                                                          \
    for (int i=0;i<4;i++)                                                      \
      gll16((const char*)xm + ((size_t)(m0+arow+i*8)*384 + k0_)*2 + osw,       \
            Ab_ + (w*4+i)*1024);                                               \
    _Pragma("unroll")                                                          \
    for (int i=0;i<6;i++)                                                      \
      gll16((const char*)wpack + ((size_t)(h*192+brow+i*8)*384 + k0_)*2 + osw, \
            Bb_ + (w*6+i)*1024);                                               \
  } while(0)

  K3_STAGE(0, 0);
  __syncthreads();
  int cur = 0;
  const int rbase = w*32;
  for (int t=0; t<6; ++t){
    if (t < 5) K3_STAGE(t+1, cur^1);
    const u16* Ab = smem + cur*8192;
    const u16* Bb = smem + 16384 + cur*12288;
    #pragma unroll
    for (int kk=0; kk<64; kk+=32){
      const int sc = (((kk>>3)+hi) ^ (lc&7))*8;
      bf16x8 a0 = *(const bf16x8*)&Ab[(rbase +      lc)*64 + sc];
      bf16x8 a1 = *(const bf16x8*)&Ab[(rbase + 16 + lc)*64 + sc];
      #pragma unroll
      for (int j=0;j<12;j++){
        bf16x8 bb = *(const bf16x8*)&Bb[(j*16 + lc)*64 + sc];
        acc[0][j] = MFMA16(a0, bb, acc[0][j]);
        acc[1][j] = MFMA16(a1, bb, acc[1][j]);
      }
    }
    __syncthreads();
    cur ^= 1;
  }
  #undef K3_STAGE

  // ---- epilogue (fast-math transcendentals) ----
  const float tq = temperature[h];
  const int b = m0 >> 12;
  const int mtile = (m0 >> 7) & 31;
  const size_t bh = (size_t)b*8 + h;
  const int bb0 = h*192;
  float biasq[3], biask[3], biasv[3], biasg[3];
  #pragma unroll
  for (int j=0;j<3;j++){
    biasq[j] = bpack[bb0       + j*16 + lc];
    biask[j] = bpack[bb0 + 48  + j*16 + lc];
    biasv[j] = bpack[bb0 + 96  + j*16 + lc];
    biasg[j] = bpack[bb0 + 144 + j*16 + lc];
  }
  u16* kT = smem;          // [48][136]
  u16* vT = smem + 6528;   // [48][136]
  float ksp[3] = {0.f, 0.f, 0.f};

  #pragma unroll
  for (int i=0;i<2;i++){
    ushort4 kst[3], vst[3];
    #pragma unroll
    for (int r=0;r<4;r++){
      int m = m0 + w*32 + i*16 + hi*4 + r;
      int n = m & 4095;
      size_t rowq = (bh*4096 + n)*48;
      float q0=(acc[i][0][r]+biasq[0])*tq;
      float q1=(acc[i][1][r]+biasq[1])*tq;
      float q2=(acc[i][2][r]+biasq[2])*tq;
      qh[rowq +      lc] = f2bf(__expf(q0));
      qh[rowq + 16 + lc] = f2bf(__expf(q1));
      qh[rowq + 32 + lc] = f2bf(__expf(q2));
      float s0=acc[i][3][r]+biask[0];
      float s1=acc[i][4][r]+biask[1];
      float s2=acc[i][5][r]+biask[2];
      float mk = fmaxf(s0,fmaxf(s1,s2));
      mk = fmaxf(mk, __shfl_xor(mk,1,64));
      mk = fmaxf(mk, __shfl_xor(mk,2,64));
      mk = fmaxf(mk, __shfl_xor(mk,4,64));
      mk = fmaxf(mk, __shfl_xor(mk,8,64));
      float k0e = __expf(s0-mk), k1e = __expf(s1-mk), k2e = __expf(s2-mk);
      ksp[0] += k0e; ksp[1] += k1e; ksp[2] += k2e;
      u16 kq0=f2bf(k0e), kq1=f2bf(k1e), kq2=f2bf(k2e);
      u16 vq[3];
      #pragma unroll
      for (int j=0;j<3;j++){
        float vv = acc[i][6+j][r] + biasv[j];
        float gg = acc[i][9+j][r] + biasg[j];
        float sg = __builtin_amdgcn_rcpf(1.f + __expf(-gg));
        vq[j] = f2bf(vv*sg);
      }
      if (r==0){ kst[0].x=kq0; kst[1].x=kq1; kst[2].x=kq2; vst[0].x=vq[0]; vst[1].x=vq[1]; vst[2].x=vq[2]; }
      if (r==1){ kst[0].y=kq0; kst[1].y=kq1; kst[2].y=kq2; vst[0].y=vq[0]; vst[1].y=vq[1]; vst[2].y=vq[2]; }
      if (r==2){ kst[0].z=kq0; kst[1].z=kq1; kst[2].z=kq2; vst[0].z=vq[0]; vst[1].z=vq[1]; vst[2].z=vq[2]; }
      if (r==3){ kst[0].w=kq0; kst[1].w=kq1; kst[2].w=kq2; vst[0].w=vq[0]; vst[1].w=vq[1]; vst[2].w=vq[2]; }
    }
    int mb = w*32 + i*16 + hi*4;
    #pragma unroll
    for (int j=0;j<3;j++){
      *(ushort4*)&kT[(j*16+lc)*136 + mb] = kst[j];
      *(ushort4*)&vT[(j*16+lc)*136 + mb] = vst[j];
    }
  }
  __syncthreads();

  bf16x8 af[3], bfv[3];
  #pragma unroll
  for (int da=0;da<3;da++) af[da]  = *(const bf16x8*)&kT[(da*16+lc)*136 + w*32 + hi*8];
  #pragma unroll
  for (int eb=0;eb<3;eb++) bfv[eb] = *(const bf16x8*)&vT[(eb*16+lc)*136 + w*32 + hi*8];
  f32x4 a2[3][3];
  #pragma unroll
  for (int da=0;da<3;da++)
    #pragma unroll
    for (int eb=0;eb<3;eb++)
      a2[da][eb] = MFMA16(af[da], bfv[eb], zf);
  __syncthreads();
  float* pb = (float*)smem + w*2304;
  #pragma unroll
  for (int da=0;da<3;da++)
    #pragma unroll
    for (int eb=0;eb<3;eb++)
      #pragma unroll
      for (int rr=0;rr<4;rr++)
        pb[(da*16 + hi*4 + rr)*48 + eb*16 + lc] = a2[da][eb][rr];
  __syncthreads();
  {
    float* p0 = (float*)smem;
    float* dst = pkv + ((size_t)bh*32 + mtile)*2304;
    for (int u=tid; u<2304; u+=256)
      dst[u] = p0[u] + p0[2304+u] + p0[4608+u] + p0[6912+u];
  }
  #pragma unroll
  for (int j=0;j<3;j++){
    ksp[j] += __shfl_xor(ksp[j],16,64);
    ksp[j] += __shfl_xor(ksp[j],32,64);
  }
  __syncthreads();
  {
    float* kr = (float*)smem;           // [4][48]
    if (hi==0){ kr[w*48+lc]=ksp[0]; kr[w*48+16+lc]=ksp[1]; kr[w*48+32+lc]=ksp[2]; }
    __syncthreads();
    if (tid < 48){
      float* ds = pks + ((size_t)bh*32 + mtile)*48;
      ds[tid] = kr[tid] + kr[48+tid] + kr[96+tid] + kr[144+tid];
    }
  }
}

// ---------------- k5: reduce partials -> kvp[e][d] bf16 (64x64, ksum row48)
__global__ __launch_bounds__(256) void k5_red(
    const float* __restrict__ pkv, const float* __restrict__ pks,
    u16* __restrict__ kvp)
{
  __shared__ float sm[2304];
  __shared__ float ks[48];
  int bh = blockIdx.x, tid = threadIdx.x;
  const float* base = pkv + (size_t)bh*32*2304;
  for (int u=tid; u<2304; u+=256){
    float v = 0.f;
    #pragma unroll
    for (int m=0;m<32;m++) v += base[(size_t)m*2304 + u];
    sm[u] = v;
  }
  if (tid < 48){
    const float* bk = pks + (size_t)bh*32*48 + tid;
    float v = 0.f;
    #pragma unroll
    for (int m=0;m<32;m++) v += bk[m*48];
    ks[tid] = v;
  }
  __syncthreads();
  for (int u=tid; u<4096; u+=256){
    int e = u >> 6, d = u & 63;
    float v = 0.f;
    if (e < 48 && d < 48)       v = sm[d*48 + e];
    else if (e == 48 && d < 48) v = ks[d];
    kvp[((size_t)bh*64 + e)*64 + d] = f2bf(v);
  }
}

// ---------------- k6: num/den -> a_hat bf16 [B,N,C] (qh 48-wide) ----------
__global__ __launch_bounds__(256) void k6_num(
    const u16* __restrict__ qh, const u16* __restrict__ kvp, u16* __restrict__ ah)
{
  __shared__ __align__(16) u16 As[256*64]; // 32KB
  __shared__ __align__(16) u16 Bs[64*64];  // 8KB
  const int bh = blockIdx.x >> 4, nc = blockIdx.x & 15;
  const int tid = threadIdx.x, w = tid>>6, l = tid&63;
  const int lc = l & 15, hi = l >> 4;
  const f32x4 zf = {0.f,0.f,0.f,0.f};
  const uint4 z4 = {0,0,0,0};
  const u16* gq = qh + ((size_t)bh*4096 + nc*256)*48;
  #pragma unroll
  for (int it=0; it<8; ++it){
    int s = it*256 + tid;
    int row = s>>3, c = s&7, g = c ^ (row&7);
    ((uint4*)As)[s] = (g < 6) ? *(const uint4*)(gq + (size_t)row*48 + g*8) : z4;
  }
  const u16* gk = kvp + (size_t)bh*4096;
  #pragma unroll
  for (int it=0; it<2; ++it){
    int s = it*256 + tid;
    int row = s>>3, c = s&7, g = c ^ (row&7);
    ((uint4*)Bs)[s] = *(const uint4*)(gk + (size_t)row*64 + g*8);
  }
  __syncthreads();
  f32x4 acc[4][4];
  #pragma unroll
  for (int i=0;i<4;i++)
    #pragma unroll
    for (int j=0;j<4;j++) acc[i][j] = zf;
  const int rbase = w*64;
  #pragma unroll
  for (int kk=0; kk<64; kk+=32){
    const int sc = (((kk>>3)+hi) ^ (lc&7))*8;
    bf16x8 a[4], bb[4];
    #pragma unroll
    for (int i=0;i<4;i++) a[i]  = *(const bf16x8*)&As[(rbase + i*16 + lc)*64 + sc];
    #pragma unroll
    for (int j=0;j<4;j++) bb[j] = *(const bf16x8*)&Bs[(j*16 + lc)*64 + sc];
    #pragma unroll
    for (int i=0;i<4;i++)
      #pragma unroll
      for (int j=0;j<4;j++)
        acc[i][j] = MFMA16(a[i], bb[j], acc[i][j]);
  }
  const int b = bh >> 3, h = bh & 7;
  #pragma unroll
  for (int i=0;i<4;i++){
    #pragma unroll
    for (int r=0;r<4;r++){
      float den = __shfl(acc[i][3][r], l & 48, 64) + EPSF;
      float rd = __builtin_amdgcn_rcpf(den);
      int n = nc*256 + rbase + i*16 + hi*4 + r;
      size_t ob = ((size_t)b*4096 + n)*384 + h*48;
      ah[ob +      lc] = f2bf(acc[i][0][r]*rd);
      ah[ob + 16 + lc] = f2bf(acc[i][1][r]*rd);
      ah[ob + 32 + lc] = f2bf(acc[i][2][r]*rd);
    }
  }
}

// ---------------- k7: out = a_hat @ wo^T + bo (fp32), dbuf prefetch -------
__global__ __launch_bounds__(256) void k7_gemm_out(
    const u16* __restrict__ ah, const u16* __restrict__ wob,
    const float* __restrict__ bo, float* __restrict__ out)
{
  __shared__ __align__(16) u16 smem[32768];  // 64KB dbuf
  const int m0 = blockIdx.x * 128;
  const int n0 = blockIdx.y * 128;
  const int tid = threadIdx.x, w = tid>>6, l = tid&63;
  const int lc = l & 15, hi = l >> 4;
  const int osw = ((l&7) ^ (l>>3))*16;
  const f32x4 zf = {0.f,0.f,0.f,0.f};
  f32x4 acc[4][4];
  #pragma unroll
  for (int i=0;i<4;i++)
    #pragma unroll
    for (int j=0;j<4;j++) acc[i][j] = zf;

  const int srow = (w*4)*8 + (l>>3);

  #define K7_STAGE(T, BUF) do {                                            \
    const int k0_ = (T)*64;                                                \
    char* Ab_ = (char*)(smem + (BUF)*8192);                                \
    char* Bb_ = (char*)(smem + 16384 + (BUF)*8192);                        \
    _Pragma("unroll")                                                      \
    for (int i=0;i<4;i++){                                                 \
      gll16((const char*)ah  + ((size_t)(m0+srow+i*8)*384 + k0_)*2 + osw,  \
            Ab_ + (w*4+i)*1024);                                           \
      gll16((const char*)wob + ((size_t)(n0+srow+i*8)*384 + k0_)*2 + osw,  \
            Bb_ + (w*4+i)*1024);                                           \
    }                                                                      \
  } while(0)

  K7_STAGE(0, 0);
  __syncthreads();
  int cur = 0;
  for (int t_=0; t_<6; ++t_){
    if (t_ < 5) K7_STAGE(t_+1, cur^1);
    const u16* As = smem + cur*8192;
    const u16* Bs = smem + 16384 + cur*8192;
    const int wr = (w>>1)*64, wc = (w&1)*64;
    #pragma unroll
    for (int kk=0; kk<64; kk+=32){
      const int sc = (((kk>>3)+hi) ^ (lc&7))*8;
      bf16x8 a[4], bb[4];
      #pragma unroll
      for (int i=0;i<4;i++) a[i]  = *(const bf16x8*)&As[(wr + i*16 + lc)*64 + sc];
      #pragma unroll
      for (int j=0;j<4;j++) bb[j] = *(const bf16x8*)&Bs[(wc + j*16 + lc)*64 + sc];
      #pragma unroll
      for (int i=0;i<4;i++)
        #pragma unroll
        for (int j=0;j<4;j++)
          acc[i][j] = MFMA16(a[i], bb[j], acc[i][j]);
    }
    __syncthreads();
    cur ^= 1;
  }
  #undef K7_STAGE
  const int wr=(w>>1)*64, wc=(w&1)*64;
  #pragma unroll
  for (int j=0;j<4;j++){
    int n = n0 + wc + j*16 + lc;
    float bias = bo[n];
    #pragma unroll
    for (int i=0;i<4;i++)
      #pragma unroll
      for (int r=0;r<4;r++){
        int m = m0 + wr + i*16 + hi*4 + r;
        out[(size_t)m*384 + n] = acc[i][j][r] + bias;
      }
  }
}

extern "C" void kernel_launch(void* const* d_in, const int* in_sizes, int n_in,
                              void* d_out, int out_size, void* d_ws, size_t ws_size,
                              hipStream_t stream)
{
  const float* x    = (const float*)d_in[0];
  const float* wq   = (const float*)d_in[1];
  const float* bq   = (const float*)d_in[2];
  const float* wk   = (const float*)d_in[3];
  const float* bk   = (const float*)d_in[4];
  const float* wv   = (const float*)d_in[5];
  const float* bv   = (const float*)d_in[6];
  const float* wg   = (const float*)d_in[7];
  const float* bg   = (const float*)d_in[8];
  const float* wo   = (const float*)d_in[9];
  const float* bo   = (const float*)d_in[10];
  const float* temp = (const float*)d_in[11];
  const float* dw_w = (const float*)d_in[12];
  const float* dw_b = (const float*)d_in[13];
  const float* pw_w = (const float*)d_in[14];
  const float* pw_b = (const float*)d_in[15];
  float* out = (float*)d_out;
  char* ws = (char*)d_ws;

  u16*   t       = (u16*)(ws + 0);
  float* pkv     = (float*)(ws + 0);          // 18874368  [64][32][2304] f32
  float* pks     = (float*)(ws + 18874368);   // 393216    [64][32][48] f32
  u16*   ah      = (u16*)(ws + 0);            // 25165824  (k6 out, k7 in)
  u16*   xm      = (u16*)(ws + 25165824);     // 25165824
  u16*   qh      = (u16*)(ws + 50331648);     // 25165824  [B,H,N,48]
  u16*   wpack   = (u16*)(ws + 83886080);     // 1179648
  u16*   pwb     = (u16*)(ws + 85065728);     // 294912
  u16*   wob     = (u16*)(ws + 85360640);     // 294912
  float* bpack   = (float*)(ws + 85655552);   // 6144
  u16*   kvp     = (u16*)(ws + 85661696);     // 524288  [64][64][64] bf16

  k01_prep_dw<<<6528, 256, 0, stream>>>(wq,bq,wk,bk,wv,bv,wg,bg,pw_w,wo,
                                        wpack,pwb,wob,bpack,
                                        x, dw_w, dw_b, t);
  k2_gemm_pw<<<dim3(256,3), 256, 0, stream>>>(t, pwb, x, pw_b, xm);
  k3_gemm_qkvg<<<dim3(8,256), 256, 0, stream>>>(xm, wpack, bpack, temp, qh, pkv, pks);
  k5_red<<<64, 256, 0, stream>>>(pkv, pks, kvp);
  k6_num<<<1024, 256, 0, stream>>>(qh, kvp, ah);
  k7_gemm_out<<<dim3(256,3), 256, 0, stream>>>(ah, wob, bo, out);
}

// Round 14
// 172.460 us; speedup vs baseline: 1.1357x; 1.0115x over previous
//
#include <hip/hip_runtime.h>
#include <math.h>

#define EPSF 1e-6f

typedef __attribute__((ext_vector_type(8))) short bf16x8;
typedef __attribute__((ext_vector_type(4))) float f32x4;
typedef unsigned short u16;
typedef unsigned int u32;

#define MFMA16(a,b,c) __builtin_amdgcn_mfma_f32_16x16x32_bf16((a),(b),(c),0,0,0)

__device__ __forceinline__ u16 f2bf(float f){
  u32 x = __builtin_bit_cast(u32, f);
  u32 r = (x + 0x7fffu + ((x >> 16) & 1u)) >> 16;
  return (u16)r;
}
__device__ __forceinline__ void gll16(const void* g, void* l){
  __builtin_amdgcn_global_load_lds(
      (const __attribute__((address_space(1))) u32*)g,
      (__attribute__((address_space(3))) u32*)l, 16, 0, 0);
}

// ---------------- k01: weight pack (blocks 0..3455) + dw conv (3456..6527)
__global__ __launch_bounds__(256) void k01_prep_dw(
    const float* __restrict__ wq, const float* __restrict__ bq,
    const float* __restrict__ wk, const float* __restrict__ bk,
    const float* __restrict__ wv, const float* __restrict__ bv,
    const float* __restrict__ wg, const float* __restrict__ bg,
    const float* __restrict__ pw_w, const float* __restrict__ wo,
    u16* __restrict__ wpack, u16* __restrict__ pwb, u16* __restrict__ wob,
    float* __restrict__ bpack,
    const float* __restrict__ x, const float* __restrict__ dw_w,
    const float* __restrict__ dw_b, u16* __restrict__ t)
{
  if (blockIdx.x < 3456){
    int idx = blockIdx.x*256 + threadIdx.x;
    const int NW = 1536*384;
    if (idx < NW) {
      int r = idx / 384, c = idx - r*384;
      int h = r / 192, s = (r % 192)/48, d = r % 48;
      const float* w = (s==0)?wq:(s==1)?wk:(s==2)?wv:wg;
      wpack[idx] = f2bf(w[(h*48+d)*384 + c]);
      if (c==0){
        const float* b = (s==0)?bq:(s==1)?bk:(s==2)?bv:bg;
        bpack[r] = b[h*48+d];
      }
    } else if (idx < NW + 147456) {
      pwb[idx - NW] = f2bf(pw_w[idx - NW]);
    } else if (idx < NW + 2*147456) {
      wob[idx - NW - 147456] = f2bf(wo[idx - NW - 147456]);
    }
    return;
  }
  int idx = (blockIdx.x - 3456)*256 + threadIdx.x;   // 786432 threads
  int c4 = idx % 96; int rest = idx / 96;
  int jg = rest & 15; rest >>= 4;
  int i = rest & 63; int b = rest >> 6;
  int c0 = c4*4, j0 = jg*4;
  float wf[36];
  {
    const float4* wp = (const float4*)(dw_w + c0*9);
    #pragma unroll
    for (int k=0;k<9;k++){
      float4 v = wp[k];
      wf[4*k] = v.x; wf[4*k+1] = v.y; wf[4*k+2] = v.z; wf[4*k+3] = v.w;
    }
  }
  float4 bias = *(const float4*)(dw_b + c0);
  float acc[4][4];
  #pragma unroll
  for (int tk=0;tk<4;tk++){
    acc[tk][0]=bias.x; acc[tk][1]=bias.y; acc[tk][2]=bias.z; acc[tk][3]=bias.w;
  }
  const float* xb = x + ((size_t)b<<12)*384;
  #pragma unroll
  for (int di=-1; di<=1; ++di){
    int ii = i+di; if ((unsigned)ii >= 64u) continue;
    #pragma unroll
    for (int dj=-1; dj<=4; ++dj){
      int jj = j0+dj; if ((unsigned)jj >= 64u) continue;
      float4 xv = *(const float4*)(xb + (size_t)((ii<<6)+jj)*384 + c0);
      #pragma unroll
      for (int tk=0;tk<4;tk++){
        const int dd = dj - tk;
        if (dd < -1 || dd > 1) continue;
        const int tap = (di+1)*3 + (dd+1);
        acc[tk][0] = fmaf(xv.x, wf[0*9+tap], acc[tk][0]);
        acc[tk][1] = fmaf(xv.y, wf[1*9+tap], acc[tk][1]);
        acc[tk][2] = fmaf(xv.z, wf[2*9+tap], acc[tk][2]);
        acc[tk][3] = fmaf(xv.w, wf[3*9+tap], acc[tk][3]);
      }
    }
  }
  int mbase = (b<<12) + (i<<6) + j0;
  #pragma unroll
  for (int tk=0;tk<4;tk++){
    ushort4 o; o.x=f2bf(acc[tk][0]); o.y=f2bf(acc[tk][1]);
    o.z=f2bf(acc[tk][2]); o.w=f2bf(acc[tk][3]);
    *(ushort4*)(t + (size_t)(mbase+tk)*384 + c0) = o;
  }
}

// ---------------- k2: xm = bf16( x + t @ pw^T + pw_b ), dbuf prefetch -----
__global__ __launch_bounds__(256) void k2_gemm_pw(
    const u16* __restrict__ t, const u16* __restrict__ pwb,
    const float* __restrict__ x, const float* __restrict__ pw_b,
    u16* __restrict__ xm)
{
  __shared__ __align__(16) u16 smem[32768];  // 64KB: A dbuf 2x16KB, B dbuf 2x16KB
  const int m0 = blockIdx.x * 128;
  const int n0 = blockIdx.y * 128;
  const int tid = threadIdx.x, w = tid>>6, l = tid&63;
  const int lc = l & 15, hi = l >> 4;
  const int osw = ((l&7) ^ (l>>3))*16;
  const f32x4 zf = {0.f,0.f,0.f,0.f};
  f32x4 acc[4][4];
  #pragma unroll
  for (int i=0;i<4;i++)
    #pragma unroll
    for (int j=0;j<4;j++) acc[i][j] = zf;

  const int srow = (w*4)*8 + (l>>3);

  #define K2_STAGE(T, BUF) do {                                            \
    const int k0_ = (T)*64;                                                \
    char* Ab_ = (char*)(smem + (BUF)*8192);                                \
    char* Bb_ = (char*)(smem + 16384 + (BUF)*8192);                        \
    _Pragma("unroll")                                                      \
    for (int i=0;i<4;i++){                                                 \
      gll16((const char*)t   + ((size_t)(m0+srow+i*8)*384 + k0_)*2 + osw,  \
            Ab_ + (w*4+i)*1024);                                           \
      gll16((const char*)pwb + ((size_t)(n0+srow+i*8)*384 + k0_)*2 + osw,  \
            Bb_ + (w*4+i)*1024);                                           \
    }                                                                      \
  } while(0)

  K2_STAGE(0, 0);
  __syncthreads();
  int cur = 0;
  for (int t_=0; t_<6; ++t_){
    if (t_ < 5) K2_STAGE(t_+1, cur^1);
    const u16* As = smem + cur*8192;
    const u16* Bs = smem + 16384 + cur*8192;
    const int wr = (w>>1)*64, wc = (w&1)*64;
    #pragma unroll
    for (int kk=0; kk<64; kk+=32){
      const int sc = (((kk>>3)+hi) ^ (lc&7))*8;
      bf16x8 a[4], bb[4];
      #pragma unroll
      for (int i=0;i<4;i++) a[i]  = *(const bf16x8*)&As[(wr + i*16 + lc)*64 + sc];
      #pragma unroll
      for (int j=0;j<4;j++) bb[j] = *(const bf16x8*)&Bs[(wc + j*16 + lc)*64 + sc];
      #pragma unroll
      for (int i=0;i<4;i++)
        #pragma unroll
        for (int j=0;j<4;j++)
          acc[i][j] = MFMA16(a[i], bb[j], acc[i][j]);
    }
    __syncthreads();
    cur ^= 1;
  }
  #undef K2_STAGE
  const int wr=(w>>1)*64, wc=(w&1)*64;
  #pragma unroll
  for (int j=0;j<4;j++){
    int n = n0 + wc + j*16 + lc;
    float bias = pw_b[n];
    #pragma unroll
    for (int i=0;i<4;i++)
      #pragma unroll
      for (int r=0;r<4;r++){
        int m = m0 + wr + i*16 + hi*4 + r;
        float v = acc[i][j][r] + x[(size_t)m*384 + n] + bias;
        xm[(size_t)m*384 + n] = f2bf(v);
      }
  }
}

// ---------------- k3: fused QKVG GEMM (grid (256,8); coalesced qh store) --
__global__ __launch_bounds__(256) void k3_gemm_qkvg(
    const u16* __restrict__ xm, const u16* __restrict__ wpack,
    const float* __restrict__ bpack, const float* __restrict__ temperature,
    u16* __restrict__ qh, float* __restrict__ pkv, float* __restrict__ pks)
{
  __shared__ __align__(16) u16 smem[40960];   // 80KB
  const int m0 = blockIdx.x * 128;
  const int h  = blockIdx.y;
  const int tid = threadIdx.x, w = tid>>6, l = tid&63;
  const int lc = l & 15, hi = l >> 4;
  const int osw = ((l&7) ^ (l>>3))*16;
  const f32x4 zf = {0.f,0.f,0.f,0.f};
  f32x4 acc[2][12];
  #pragma unroll
  for (int i=0;i<2;i++)
    #pragma unroll
    for (int j=0;j<12;j++) acc[i][j] = zf;

  const int arow = (w*4)*8 + (l>>3);
  const int brow = (w*6)*8 + (l>>3);

  #define K3_STAGE(T, BUF) do {                                                \
    const int k0_ = (T)*64;                                                    \
    char* Ab_ = (char*)(smem + (BUF)*8192);                                    \
    char* Bb_ = (char*)(smem + 16384 + (BUF)*12288);                           \
    _Pragma("unroll")                                                          \
    for (int i=0;i<4;i++)                                                      \
      gll16((const char*)xm + ((size_t)(m0+arow+i*8)*384 + k0_)*2 + osw,       \
            Ab_ + (w*4+i)*1024);                                               \
    _Pragma("unroll")                                                          \
    for (int i=0;i<6;i++)                                                      \
      gll16((const char*)wpack + ((size_t)(h*192+brow+i*8)*384 + k0_)*2 + osw, \
            Bb_ + (w*6+i)*1024);                                               \
  } while(0)

  K3_STAGE(0, 0);
  __syncthreads();
  int cur = 0;
  const int rbase = w*32;
  for (int t=0; t<6; ++t){
    if (t < 5) K3_STAGE(t+1, cur^1);
    const u16* Ab = smem + cur*8192;
    const u16* Bb = smem + 16384 + cur*12288;
    #pragma unroll
    for (int kk=0; kk<64; kk+=32){
      const int sc = (((kk>>3)+hi) ^ (lc&7))*8;
      bf16x8 a0 = *(const bf16x8*)&Ab[(rbase +      lc)*64 + sc];
      bf16x8 a1 = *(const bf16x8*)&Ab[(rbase + 16 + lc)*64 + sc];
      #pragma unroll
      for (int j=0;j<12;j++){
        bf16x8 bb = *(const bf16x8*)&Bb[(j*16 + lc)*64 + sc];
        acc[0][j] = MFMA16(a0, bb, acc[0][j]);
        acc[1][j] = MFMA16(a1, bb, acc[1][j]);
      }
    }
    __syncthreads();
    cur ^= 1;
  }
  #undef K3_STAGE

  // ---- epilogue ----
  const float tq = temperature[h];
  const int b = m0 >> 12;
  const int mtile = (m0 >> 7) & 31;
  const size_t bh = (size_t)b*8 + h;
  const int bb0 = h*192;
  float biasq[3], biask[3], biasv[3], biasg[3];
  #pragma unroll
  for (int j=0;j<3;j++){
    biasq[j] = bpack[bb0       + j*16 + lc];
    biask[j] = bpack[bb0 + 48  + j*16 + lc];
    biasv[j] = bpack[bb0 + 96  + j*16 + lc];
    biasg[j] = bpack[bb0 + 144 + j*16 + lc];
  }
  u16* kT  = smem;          // [48][136]  bytes 0..13055
  u16* vT  = smem + 6528;   // [48][136]  bytes 13056..26111
  u16* qls = smem + 16384;  // [128][48]  bytes 32768..45055 (q staging)
  float ksp[3] = {0.f, 0.f, 0.f};

  #pragma unroll
  for (int i=0;i<2;i++){
    ushort4 kst[3], vst[3];
    #pragma unroll
    for (int r=0;r<4;r++){
      int row = w*32 + i*16 + hi*4 + r;
      float q0=(acc[i][0][r]+biasq[0])*tq;
      float q1=(acc[i][1][r]+biasq[1])*tq;
      float q2=(acc[i][2][r]+biasq[2])*tq;
      qls[row*48 +      lc] = f2bf(__expf(q0));
      qls[row*48 + 16 + lc] = f2bf(__expf(q1));
      qls[row*48 + 32 + lc] = f2bf(__expf(q2));
      float s0=acc[i][3][r]+biask[0];
      float s1=acc[i][4][r]+biask[1];
      float s2=acc[i][5][r]+biask[2];
      float mk = fmaxf(s0,fmaxf(s1,s2));
      mk = fmaxf(mk, __shfl_xor(mk,1,64));
      mk = fmaxf(mk, __shfl_xor(mk,2,64));
      mk = fmaxf(mk, __shfl_xor(mk,4,64));
      mk = fmaxf(mk, __shfl_xor(mk,8,64));
      float k0e = __expf(s0-mk), k1e = __expf(s1-mk), k2e = __expf(s2-mk);
      ksp[0] += k0e; ksp[1] += k1e; ksp[2] += k2e;
      u16 kq0=f2bf(k0e), kq1=f2bf(k1e), kq2=f2bf(k2e);
      u16 vq[3];
      #pragma unroll
      for (int j=0;j<3;j++){
        float vv = acc[i][6+j][r] + biasv[j];
        float gg = acc[i][9+j][r] + biasg[j];
        float sg = __builtin_amdgcn_rcpf(1.f + __expf(-gg));
        vq[j] = f2bf(vv*sg);
      }
      if (r==0){ kst[0].x=kq0; kst[1].x=kq1; kst[2].x=kq2; vst[0].x=vq[0]; vst[1].x=vq[1]; vst[2].x=vq[2]; }
      if (r==1){ kst[0].y=kq0; kst[1].y=kq1; kst[2].y=kq2; vst[0].y=vq[0]; vst[1].y=vq[1]; vst[2].y=vq[2]; }
      if (r==2){ kst[0].z=kq0; kst[1].z=kq1; kst[2].z=kq2; vst[0].z=vq[0]; vst[1].z=vq[1]; vst[2].z=vq[2]; }
      if (r==3){ kst[0].w=kq0; kst[1].w=kq1; kst[2].w=kq2; vst[0].w=vq[0]; vst[1].w=vq[1]; vst[2].w=vq[2]; }
    }
    int mb = w*32 + i*16 + hi*4;
    #pragma unroll
    for (int j=0;j<3;j++){
      *(ushort4*)&kT[(j*16+lc)*136 + mb] = kst[j];
      *(ushort4*)&vT[(j*16+lc)*136 + mb] = vst[j];
    }
  }
  __syncthreads();

  // coalesced qh store: [128][48] contiguous -> 768 uint4 linear
  {
    size_t gqb = ((size_t)bh*4096 + (m0 & 4095))*48;
    #pragma unroll
    for (int it=0; it<3; ++it){
      int s = it*256 + tid;
      *(uint4*)(qh + gqb + (size_t)s*8) = *(const uint4*)&qls[s*8];
    }
  }

  bf16x8 af[3], bfv[3];
  #pragma unroll
  for (int da=0;da<3;da++) af[da]  = *(const bf16x8*)&kT[(da*16+lc)*136 + w*32 + hi*8];
  #pragma unroll
  for (int eb=0;eb<3;eb++) bfv[eb] = *(const bf16x8*)&vT[(eb*16+lc)*136 + w*32 + hi*8];
  f32x4 a2[3][3];
  #pragma unroll
  for (int da=0;da<3;da++)
    #pragma unroll
    for (int eb=0;eb<3;eb++)
      a2[da][eb] = MFMA16(af[da], bfv[eb], zf);
  __syncthreads();
  float* pb = (float*)smem + w*2304;
  #pragma unroll
  for (int da=0;da<3;da++)
    #pragma unroll
    for (int eb=0;eb<3;eb++)
      #pragma unroll
      for (int rr=0;rr<4;rr++)
        pb[(da*16 + hi*4 + rr)*48 + eb*16 + lc] = a2[da][eb][rr];
  __syncthreads();
  {
    float* p0 = (float*)smem;
    float* dst = pkv + ((size_t)bh*32 + mtile)*2304;
    for (int u=tid; u<2304; u+=256)
      dst[u] = p0[u] + p0[2304+u] + p0[4608+u] + p0[6912+u];
  }
  #pragma unroll
  for (int j=0;j<3;j++){
    ksp[j] += __shfl_xor(ksp[j],16,64);
    ksp[j] += __shfl_xor(ksp[j],32,64);
  }
  __syncthreads();
  {
    float* kr = (float*)smem;           // [4][48]
    if (hi==0){ kr[w*48+lc]=ksp[0]; kr[w*48+16+lc]=ksp[1]; kr[w*48+32+lc]=ksp[2]; }
    __syncthreads();
    if (tid < 48){
      float* ds = pks + ((size_t)bh*32 + mtile)*48;
      ds[tid] = kr[tid] + kr[48+tid] + kr[96+tid] + kr[144+tid];
    }
  }
}

// ---------------- k5: reduce partials -> kvp[e][d] bf16 (64x64, ksum row48)
__global__ __launch_bounds__(256) void k5_red(
    const float* __restrict__ pkv, const float* __restrict__ pks,
    u16* __restrict__ kvp)
{
  __shared__ float sm[2304];
  __shared__ float ks[48];
  int bh = blockIdx.x, tid = threadIdx.x;
  const float* base = pkv + (size_t)bh*32*2304;
  for (int u=tid; u<2304; u+=256){
    float v = 0.f;
    #pragma unroll
    for (int m=0;m<32;m++) v += base[(size_t)m*2304 + u];
    sm[u] = v;
  }
  if (tid < 48){
    const float* bk = pks + (size_t)bh*32*48 + tid;
    float v = 0.f;
    #pragma unroll
    for (int m=0;m<32;m++) v += bk[m*48];
    ks[tid] = v;
  }
  __syncthreads();
  for (int u=tid; u<4096; u+=256){
    int e = u >> 6, d = u & 63;
    float v = 0.f;
    if (e < 48 && d < 48)       v = sm[d*48 + e];
    else if (e == 48 && d < 48) v = ks[d];
    kvp[((size_t)bh*64 + e)*64 + d] = f2bf(v);
  }
}

// ---------------- k6: num/den -> a_hat bf16 [B,N,C] (qh 48-wide) ----------
__global__ __launch_bounds__(256) void k6_num(
    const u16* __restrict__ qh, const u16* __restrict__ kvp, u16* __restrict__ ah)
{
  __shared__ __align__(16) u16 As[256*64]; // 32KB
  __shared__ __align__(16) u16 Bs[64*64];  // 8KB
  const int bh = blockIdx.x >> 4, nc = blockIdx.x & 15;
  const int tid = threadIdx.x, w = tid>>6, l = tid&63;
  const int lc = l & 15, hi = l >> 4;
  const f32x4 zf = {0.f,0.f,0.f,0.f};
  const uint4 z4 = {0,0,0,0};
  const u16* gq = qh + ((size_t)bh*4096 + nc*256)*48;
  #pragma unroll
  for (int it=0; it<8; ++it){
    int s = it*256 + tid;
    int row = s>>3, c = s&7, g = c ^ (row&7);
    ((uint4*)As)[s] = (g < 6) ? *(const uint4*)(gq + (size_t)row*48 + g*8) : z4;
  }
  const u16* gk = kvp + (size_t)bh*4096;
  #pragma unroll
  for (int it=0; it<2; ++it){
    int s = it*256 + tid;
    int row = s>>3, c = s&7, g = c ^ (row&7);
    ((uint4*)Bs)[s] = *(const uint4*)(gk + (size_t)row*64 + g*8);
  }
  __syncthreads();
  f32x4 acc[4][4];
  #pragma unroll
  for (int i=0;i<4;i++)
    #pragma unroll
    for (int j=0;j<4;j++) acc[i][j] = zf;
  const int rbase = w*64;
  #pragma unroll
  for (int kk=0; kk<64; kk+=32){
    const int sc = (((kk>>3)+hi) ^ (lc&7))*8;
    bf16x8 a[4], bb[4];
    #pragma unroll
    for (int i=0;i<4;i++) a[i]  = *(const bf16x8*)&As[(rbase + i*16 + lc)*64 + sc];
    #pragma unroll
    for (int j=0;j<4;j++) bb[j] = *(const bf16x8*)&Bs[(j*16 + lc)*64 + sc];
    #pragma unroll
    for (int i=0;i<4;i++)
      #pragma unroll
      for (int j=0;j<4;j++)
        acc[i][j] = MFMA16(a[i], bb[j], acc[i][j]);
  }
  const int b = bh >> 3, h = bh & 7;
  #pragma unroll
  for (int i=0;i<4;i++){
    #pragma unroll
    for (int r=0;r<4;r++){
      float den = __shfl(acc[i][3][r], l & 48, 64) + EPSF;
      float rd = __builtin_amdgcn_rcpf(den);
      int n = nc*256 + rbase + i*16 + hi*4 + r;
      size_t ob = ((size_t)b*4096 + n)*384 + h*48;
      ah[ob +      lc] = f2bf(acc[i][0][r]*rd);
      ah[ob + 16 + lc] = f2bf(acc[i][1][r]*rd);
      ah[ob + 32 + lc] = f2bf(acc[i][2][r]*rd);
    }
  }
}

// ---------------- k7: out = a_hat @ wo^T + bo (fp32), dbuf prefetch -------
__global__ __launch_bounds__(256) void k7_gemm_out(
    const u16* __restrict__ ah, const u16* __restrict__ wob,
    const float* __restrict__ bo, float* __restrict__ out)
{
  __shared__ __align__(16) u16 smem[32768];  // 64KB dbuf
  const int m0 = blockIdx.x * 128;
  const int n0 = blockIdx.y * 128;
  const int tid = threadIdx.x, w = tid>>6, l = tid&63;
  const int lc = l & 15, hi = l >> 4;
  const int osw = ((l&7) ^ (l>>3))*16;
  const f32x4 zf = {0.f,0.f,0.f,0.f};
  f32x4 acc[4][4];
  #pragma unroll
  for (int i=0;i<4;i++)
    #pragma unroll
    for (int j=0;j<4;j++) acc[i][j] = zf;

  const int srow = (w*4)*8 + (l>>3);

  #define K7_STAGE(T, BUF) do {                                            \
    const int k0_ = (T)*64;                                                \
    char* Ab_ = (char*)(smem + (BUF)*8192);                                \
    char* Bb_ = (char*)(smem + 16384 + (BUF)*8192);                        \
    _Pragma("unroll")                                                      \
    for (int i=0;i<4;i++){                                                 \
      gll16((const char*)ah  + ((size_t)(m0+srow+i*8)*384 + k0_)*2 + osw,  \
            Ab_ + (w*4+i)*1024);                                           \
      gll16((const char*)wob + ((size_t)(n0+srow+i*8)*384 + k0_)*2 + osw,  \
            Bb_ + (w*4+i)*1024);                                           \
    }                                                                      \
  } while(0)

  K7_STAGE(0, 0);
  __syncthreads();
  int cur = 0;
  for (int t_=0; t_<6; ++t_){
    if (t_ < 5) K7_STAGE(t_+1, cur^1);
    const u16* As = smem + cur*8192;
    const u16* Bs = smem + 16384 + cur*8192;
    const int wr = (w>>1)*64, wc = (w&1)*64;
    #pragma unroll
    for (int kk=0; kk<64; kk+=32){
      const int sc = (((kk>>3)+hi) ^ (lc&7))*8;
      bf16x8 a[4], bb[4];
      #pragma unroll
      for (int i=0;i<4;i++) a[i]  = *(const bf16x8*)&As[(wr + i*16 + lc)*64 + sc];
      #pragma unroll
      for (int j=0;j<4;j++) bb[j] = *(const bf16x8*)&Bs[(wc + j*16 + lc)*64 + sc];
      #pragma unroll
      for (int i=0;i<4;i++)
        #pragma unroll
        for (int j=0;j<4;j++)
          acc[i][j] = MFMA16(a[i], bb[j], acc[i][j]);
    }
    __syncthreads();
    cur ^= 1;
  }
  #undef K7_STAGE
  const int wr=(w>>1)*64, wc=(w&1)*64;
  #pragma unroll
  for (int j=0;j<4;j++){
    int n = n0 + wc + j*16 + lc;
    float bias = bo[n];
    #pragma unroll
    for (int i=0;i<4;i++)
      #pragma unroll
      for (int r=0;r<4;r++){
        int m = m0 + wr + i*16 + hi*4 + r;
        out[(size_t)m*384 + n] = acc[i][j][r] + bias;
      }
  }
}

extern "C" void kernel_launch(void* const* d_in, const int* in_sizes, int n_in,
                              void* d_out, int out_size, void* d_ws, size_t ws_size,
                              hipStream_t stream)
{
  const float* x    = (const float*)d_in[0];
  const float* wq   = (const float*)d_in[1];
  const float* bq   = (const float*)d_in[2];
  const float* wk   = (const float*)d_in[3];
  const float* bk   = (const float*)d_in[4];
  const float* wv   = (const float*)d_in[5];
  const float* bv   = (const float*)d_in[6];
  const float* wg   = (const float*)d_in[7];
  const float* bg   = (const float*)d_in[8];
  const float* wo   = (const float*)d_in[9];
  const float* bo   = (const float*)d_in[10];
  const float* temp = (const float*)d_in[11];
  const float* dw_w = (const float*)d_in[12];
  const float* dw_b = (const float*)d_in[13];
  const float* pw_w = (const float*)d_in[14];
  const float* pw_b = (const float*)d_in[15];
  float* out = (float*)d_out;
  char* ws = (char*)d_ws;

  u16*   t       = (u16*)(ws + 0);
  float* pkv     = (float*)(ws + 0);          // 18874368  [64][32][2304] f32
  float* pks     = (float*)(ws + 18874368);   // 393216    [64][32][48] f32
  u16*   ah      = (u16*)(ws + 0);            // 25165824  (k6 out, k7 in)
  u16*   xm      = (u16*)(ws + 25165824);     // 25165824
  u16*   qh      = (u16*)(ws + 50331648);     // 25165824  [B,H,N,48]
  u16*   wpack   = (u16*)(ws + 83886080);     // 1179648
  u16*   pwb     = (u16*)(ws + 85065728);     // 294912
  u16*   wob     = (u16*)(ws + 85360640);     // 294912
  float* bpack   = (float*)(ws + 85655552);   // 6144
  u16*   kvp     = (u16*)(ws + 85661696);     // 524288  [64][64][64] bf16

  k01_prep_dw<<<6528, 256, 0, stream>>>(wq,bq,wk,bk,wv,bv,wg,bg,pw_w,wo,
                                        wpack,pwb,wob,bpack,
                                        x, dw_w, dw_b, t);
  k2_gemm_pw<<<dim3(256,3), 256, 0, stream>>>(t, pwb, x, pw_b, xm);
  k3_gemm_qkvg<<<dim3(256,8), 256, 0, stream>>>(xm, wpack, bpack, temp, qh, pkv, pks);
  k5_red<<<64, 256, 0, stream>>>(pkv, pks, kvp);
  k6_num<<<1024, 256, 0, stream>>>(qh, kvp, ah);
  k7_gemm_out<<<dim3(256,3), 256, 0, stream>>>(ah, wob, bo, out);
}

// Round 15
// 169.733 us; speedup vs baseline: 1.1540x; 1.0161x over previous
//
#include <hip/hip_runtime.h>
#include <math.h>

#define EPSF 1e-6f

typedef __attribute__((ext_vector_type(8))) short bf16x8;
typedef __attribute__((ext_vector_type(4))) float f32x4;
typedef unsigned short u16;
typedef unsigned int u32;

#define MFMA16(a,b,c) __builtin_amdgcn_mfma_f32_16x16x32_bf16((a),(b),(c),0,0,0)

__device__ __forceinline__ u16 f2bf(float f){
  u32 x = __builtin_bit_cast(u32, f);
  u32 r = (x + 0x7fffu + ((x >> 16) & 1u)) >> 16;
  return (u16)r;
}
__device__ __forceinline__ void gll16(const void* g, void* l){
  __builtin_amdgcn_global_load_lds(
      (const __attribute__((address_space(1))) u32*)g,
      (__attribute__((address_space(3))) u32*)l, 16, 0, 0);
}

// ---------------- k01: weight pack (blocks 0..3455) + dw conv (3456..6527)
__global__ __launch_bounds__(256) void k01_prep_dw(
    const float* __restrict__ wq, const float* __restrict__ bq,
    const float* __restrict__ wk, const float* __restrict__ bk,
    const float* __restrict__ wv, const float* __restrict__ bv,
    const float* __restrict__ wg, const float* __restrict__ bg,
    const float* __restrict__ pw_w, const float* __restrict__ wo,
    u16* __restrict__ wpack, u16* __restrict__ pwb, u16* __restrict__ wob,
    float* __restrict__ bpack,
    const float* __restrict__ x, const float* __restrict__ dw_w,
    const float* __restrict__ dw_b, u16* __restrict__ t)
{
  if (blockIdx.x < 3456){
    int idx = blockIdx.x*256 + threadIdx.x;
    const int NW = 1536*384;
    if (idx < NW) {
      int r = idx / 384, c = idx - r*384;
      int h = r / 192, s = (r % 192)/48, d = r % 48;
      const float* w = (s==0)?wq:(s==1)?wk:(s==2)?wv:wg;
      wpack[idx] = f2bf(w[(h*48+d)*384 + c]);
      if (c==0){
        const float* b = (s==0)?bq:(s==1)?bk:(s==2)?bv:bg;
        bpack[r] = b[h*48+d];
      }
    } else if (idx < NW + 147456) {
      pwb[idx - NW] = f2bf(pw_w[idx - NW]);
    } else if (idx < NW + 2*147456) {
      wob[idx - NW - 147456] = f2bf(wo[idx - NW - 147456]);
    }
    return;
  }
  int idx = (blockIdx.x - 3456)*256 + threadIdx.x;   // 786432 threads
  int c4 = idx % 96; int rest = idx / 96;
  int jg = rest & 15; rest >>= 4;
  int i = rest & 63; int b = rest >> 6;
  int c0 = c4*4, j0 = jg*4;
  float wf[36];
  {
    const float4* wp = (const float4*)(dw_w + c0*9);
    #pragma unroll
    for (int k=0;k<9;k++){
      float4 v = wp[k];
      wf[4*k] = v.x; wf[4*k+1] = v.y; wf[4*k+2] = v.z; wf[4*k+3] = v.w;
    }
  }
  float4 bias = *(const float4*)(dw_b + c0);
  float acc[4][4];
  #pragma unroll
  for (int tk=0;tk<4;tk++){
    acc[tk][0]=bias.x; acc[tk][1]=bias.y; acc[tk][2]=bias.z; acc[tk][3]=bias.w;
  }
  const float* xb = x + ((size_t)b<<12)*384;
  #pragma unroll
  for (int di=-1; di<=1; ++di){
    int ii = i+di; if ((unsigned)ii >= 64u) continue;
    #pragma unroll
    for (int dj=-1; dj<=4; ++dj){
      int jj = j0+dj; if ((unsigned)jj >= 64u) continue;
      float4 xv = *(const float4*)(xb + (size_t)((ii<<6)+jj)*384 + c0);
      #pragma unroll
      for (int tk=0;tk<4;tk++){
        const int dd = dj - tk;
        if (dd < -1 || dd > 1) continue;
        const int tap = (di+1)*3 + (dd+1);
        acc[tk][0] = fmaf(xv.x, wf[0*9+tap], acc[tk][0]);
        acc[tk][1] = fmaf(xv.y, wf[1*9+tap], acc[tk][1]);
        acc[tk][2] = fmaf(xv.z, wf[2*9+tap], acc[tk][2]);
        acc[tk][3] = fmaf(xv.w, wf[3*9+tap], acc[tk][3]);
      }
    }
  }
  int mbase = (b<<12) + (i<<6) + j0;
  #pragma unroll
  for (int tk=0;tk<4;tk++){
    ushort4 o; o.x=f2bf(acc[tk][0]); o.y=f2bf(acc[tk][1]);
    o.z=f2bf(acc[tk][2]); o.w=f2bf(acc[tk][3]);
    *(ushort4*)(t + (size_t)(mbase+tk)*384 + c0) = o;
  }
}

// ---------------- k2: xm = bf16( x + t @ pw^T + pw_b ), dbuf prefetch -----
__global__ __launch_bounds__(256) void k2_gemm_pw(
    const u16* __restrict__ t, const u16* __restrict__ pwb,
    const float* __restrict__ x, const float* __restrict__ pw_b,
    u16* __restrict__ xm)
{
  __shared__ __align__(16) u16 smem[32768];  // 64KB: A dbuf 2x16KB, B dbuf 2x16KB
  const int m0 = blockIdx.x * 128;
  const int n0 = blockIdx.y * 128;
  const int tid = threadIdx.x, w = tid>>6, l = tid&63;
  const int lc = l & 15, hi = l >> 4;
  const int osw = ((l&7) ^ (l>>3))*16;
  const f32x4 zf = {0.f,0.f,0.f,0.f};
  f32x4 acc[4][4];
  #pragma unroll
  for (int i=0;i<4;i++)
    #pragma unroll
    for (int j=0;j<4;j++) acc[i][j] = zf;

  const int srow = (w*4)*8 + (l>>3);

  #define K2_STAGE(T, BUF) do {                                            \
    const int k0_ = (T)*64;                                                \
    char* Ab_ = (char*)(smem + (BUF)*8192);                                \
    char* Bb_ = (char*)(smem + 16384 + (BUF)*8192);                        \
    _Pragma("unroll")                                                      \
    for (int i=0;i<4;i++){                                                 \
      gll16((const char*)t   + ((size_t)(m0+srow+i*8)*384 + k0_)*2 + osw,  \
            Ab_ + (w*4+i)*1024);                                           \
      gll16((const char*)pwb + ((size_t)(n0+srow+i*8)*384 + k0_)*2 + osw,  \
            Bb_ + (w*4+i)*1024);                                           \
    }                                                                      \
  } while(0)

  K2_STAGE(0, 0);
  __syncthreads();
  int cur = 0;
  for (int t_=0; t_<6; ++t_){
    if (t_ < 5) K2_STAGE(t_+1, cur^1);
    const u16* As = smem + cur*8192;
    const u16* Bs = smem + 16384 + cur*8192;
    const int wr = (w>>1)*64, wc = (w&1)*64;
    #pragma unroll
    for (int kk=0; kk<64; kk+=32){
      const int sc = (((kk>>3)+hi) ^ (lc&7))*8;
      bf16x8 a[4], bb[4];
      #pragma unroll
      for (int i=0;i<4;i++) a[i]  = *(const bf16x8*)&As[(wr + i*16 + lc)*64 + sc];
      #pragma unroll
      for (int j=0;j<4;j++) bb[j] = *(const bf16x8*)&Bs[(wc + j*16 + lc)*64 + sc];
      #pragma unroll
      for (int i=0;i<4;i++)
        #pragma unroll
        for (int j=0;j<4;j++)
          acc[i][j] = MFMA16(a[i], bb[j], acc[i][j]);
    }
    __syncthreads();
    cur ^= 1;
  }
  #undef K2_STAGE
  const int wr=(w>>1)*64, wc=(w&1)*64;
  #pragma unroll
  for (int j=0;j<4;j++){
    int n = n0 + wc + j*16 + lc;
    float bias = pw_b[n];
    #pragma unroll
    for (int i=0;i<4;i++)
      #pragma unroll
      for (int r=0;r<4;r++){
        int m = m0 + wr + i*16 + hi*4 + r;
        float v = acc[i][j][r] + x[(size_t)m*384 + n] + bias;
        xm[(size_t)m*384 + n] = f2bf(v);
      }
  }
}

// ---------------- k3: fused QKVG GEMM (R12 form: direct qh store) ---------
__global__ __launch_bounds__(256) void k3_gemm_qkvg(
    const u16* __restrict__ xm, const u16* __restrict__ wpack,
    const float* __restrict__ bpack, const float* __restrict__ temperature,
    u16* __restrict__ qh, float* __restrict__ pkv, float* __restrict__ pks)
{
  __shared__ __align__(16) u16 smem[40960];   // 80KB
  const int m0 = blockIdx.x * 128;
  const int h  = blockIdx.y;
  const int tid = threadIdx.x, w = tid>>6, l = tid&63;
  const int lc = l & 15, hi = l >> 4;
  const int osw = ((l&7) ^ (l>>3))*16;
  const f32x4 zf = {0.f,0.f,0.f,0.f};
  f32x4 acc[2][12];
  #pragma unroll
  for (int i=0;i<2;i++)
    #pragma unroll
    for (int j=0;j<12;j++) acc[i][j] = zf;

  const int arow = (w*4)*8 + (l>>3);
  const int brow = (w*6)*8 + (l>>3);

  #define K3_STAGE(T, BUF) do {                                                \
    const int k0_ = (T)*64;                                                    \
    char* Ab_ = (char*)(smem + (BUF)*8192);                                    \
    char* Bb_ = (char*)(smem + 16384 + (BUF)*12288);                           \
    _Pragma("unroll")                                                          \
    for (int i=0;i<4;i++)                                                      \
      gll16((const char*)xm + ((size_t)(m0+arow+i*8)*384 + k0_)*2 + osw,       \
            Ab_ + (w*4+i)*1024);                                               \
    _Pragma("unroll")                                                          \
    for (int i=0;i<6;i++)                                                      \
      gll16((const char*)wpack + ((size_t)(h*192+brow+i*8)*384 + k0_)*2 + osw, \
            Bb_ + (w*6+i)*1024);                                               \
  } while(0)

  K3_STAGE(0, 0);
  __syncthreads();
  int cur = 0;
  const int rbase = w*32;
  for (int t=0; t<6; ++t){
    if (t < 5) K3_STAGE(t+1, cur^1);
    const u16* Ab = smem + cur*8192;
    const u16* Bb = smem + 16384 + cur*12288;
    #pragma unroll
    for (int kk=0; kk<64; kk+=32){
      const int sc = (((kk>>3)+hi) ^ (lc&7))*8;
      bf16x8 a0 = *(const bf16x8*)&Ab[(rbase +      lc)*64 + sc];
      bf16x8 a1 = *(const bf16x8*)&Ab[(rbase + 16 + lc)*64 + sc];
      #pragma unroll
      for (int j=0;j<12;j++){
        bf16x8 bb = *(const bf16x8*)&Bb[(j*16 + lc)*64 + sc];
        acc[0][j] = MFMA16(a0, bb, acc[0][j]);
        acc[1][j] = MFMA16(a1, bb, acc[1][j]);
      }
    }
    __syncthreads();
    cur ^= 1;
  }
  #undef K3_STAGE

  // ---- epilogue (fast-math transcendentals; direct 48-wide qh store) ----
  const float tq = temperature[h];
  const int b = m0 >> 12;
  const int mtile = (m0 >> 7) & 31;
  const size_t bh = (size_t)b*8 + h;
  const int bb0 = h*192;
  float biasq[3], biask[3], biasv[3], biasg[3];
  #pragma unroll
  for (int j=0;j<3;j++){
    biasq[j] = bpack[bb0       + j*16 + lc];
    biask[j] = bpack[bb0 + 48  + j*16 + lc];
    biasv[j] = bpack[bb0 + 96  + j*16 + lc];
    biasg[j] = bpack[bb0 + 144 + j*16 + lc];
  }
  u16* kT = smem;          // [48][136]
  u16* vT = smem + 6528;   // [48][136]
  float ksp[3] = {0.f, 0.f, 0.f};

  #pragma unroll
  for (int i=0;i<2;i++){
    ushort4 kst[3], vst[3];
    #pragma unroll
    for (int r=0;r<4;r++){
      int m = m0 + w*32 + i*16 + hi*4 + r;
      int n = m & 4095;
      size_t rowq = (bh*4096 + n)*48;
      float q0=(acc[i][0][r]+biasq[0])*tq;
      float q1=(acc[i][1][r]+biasq[1])*tq;
      float q2=(acc[i][2][r]+biasq[2])*tq;
      qh[rowq +      lc] = f2bf(__expf(q0));
      qh[rowq + 16 + lc] = f2bf(__expf(q1));
      qh[rowq + 32 + lc] = f2bf(__expf(q2));
      float s0=acc[i][3][r]+biask[0];
      float s1=acc[i][4][r]+biask[1];
      float s2=acc[i][5][r]+biask[2];
      float mk = fmaxf(s0,fmaxf(s1,s2));
      mk = fmaxf(mk, __shfl_xor(mk,1,64));
      mk = fmaxf(mk, __shfl_xor(mk,2,64));
      mk = fmaxf(mk, __shfl_xor(mk,4,64));
      mk = fmaxf(mk, __shfl_xor(mk,8,64));
      float k0e = __expf(s0-mk), k1e = __expf(s1-mk), k2e = __expf(s2-mk);
      ksp[0] += k0e; ksp[1] += k1e; ksp[2] += k2e;
      u16 kq0=f2bf(k0e), kq1=f2bf(k1e), kq2=f2bf(k2e);
      u16 vq[3];
      #pragma unroll
      for (int j=0;j<3;j++){
        float vv = acc[i][6+j][r] + biasv[j];
        float gg = acc[i][9+j][r] + biasg[j];
        float sg = __builtin_amdgcn_rcpf(1.f + __expf(-gg));
        vq[j] = f2bf(vv*sg);
      }
      if (r==0){ kst[0].x=kq0; kst[1].x=kq1; kst[2].x=kq2; vst[0].x=vq[0]; vst[1].x=vq[1]; vst[2].x=vq[2]; }
      if (r==1){ kst[0].y=kq0; kst[1].y=kq1; kst[2].y=kq2; vst[0].y=vq[0]; vst[1].y=vq[1]; vst[2].y=vq[2]; }
      if (r==2){ kst[0].z=kq0; kst[1].z=kq1; kst[2].z=kq2; vst[0].z=vq[0]; vst[1].z=vq[1]; vst[2].z=vq[2]; }
      if (r==3){ kst[0].w=kq0; kst[1].w=kq1; kst[2].w=kq2; vst[0].w=vq[0]; vst[1].w=vq[1]; vst[2].w=vq[2]; }
    }
    int mb = w*32 + i*16 + hi*4;
    #pragma unroll
    for (int j=0;j<3;j++){
      *(ushort4*)&kT[(j*16+lc)*136 + mb] = kst[j];
      *(ushort4*)&vT[(j*16+lc)*136 + mb] = vst[j];
    }
  }
  __syncthreads();

  bf16x8 af[3], bfv[3];
  #pragma unroll
  for (int da=0;da<3;da++) af[da]  = *(const bf16x8*)&kT[(da*16+lc)*136 + w*32 + hi*8];
  #pragma unroll
  for (int eb=0;eb<3;eb++) bfv[eb] = *(const bf16x8*)&vT[(eb*16+lc)*136 + w*32 + hi*8];
  f32x4 a2[3][3];
  #pragma unroll
  for (int da=0;da<3;da++)
    #pragma unroll
    for (int eb=0;eb<3;eb++)
      a2[da][eb] = MFMA16(af[da], bfv[eb], zf);
  __syncthreads();
  float* pb = (float*)smem + w*2304;
  #pragma unroll
  for (int da=0;da<3;da++)
    #pragma unroll
    for (int eb=0;eb<3;eb++)
      #pragma unroll
      for (int rr=0;rr<4;rr++)
        pb[(da*16 + hi*4 + rr)*48 + eb*16 + lc] = a2[da][eb][rr];
  __syncthreads();
  {
    float* p0 = (float*)smem;
    float* dst = pkv + ((size_t)bh*32 + mtile)*2304;
    for (int u=tid; u<2304; u+=256)
      dst[u] = p0[u] + p0[2304+u] + p0[4608+u] + p0[6912+u];
  }
  #pragma unroll
  for (int j=0;j<3;j++){
    ksp[j] += __shfl_xor(ksp[j],16,64);
    ksp[j] += __shfl_xor(ksp[j],32,64);
  }
  __syncthreads();
  {
    float* kr = (float*)smem;           // [4][48]
    if (hi==0){ kr[w*48+lc]=ksp[0]; kr[w*48+16+lc]=ksp[1]; kr[w*48+32+lc]=ksp[2]; }
    __syncthreads();
    if (tid < 48){
      float* ds = pks + ((size_t)bh*32 + mtile)*48;
      ds[tid] = kr[tid] + kr[48+tid] + kr[96+tid] + kr[144+tid];
    }
  }
}

// ---------------- k5: reduce partials -> kvp[e][d] bf16 (64x64, ksum row48)
__global__ __launch_bounds__(256) void k5_red(
    const float* __restrict__ pkv, const float* __restrict__ pks,
    u16* __restrict__ kvp)
{
  __shared__ float sm[2304];
  __shared__ float ks[48];
  int bh = blockIdx.x, tid = threadIdx.x;
  const float* base = pkv + (size_t)bh*32*2304;
  for (int u=tid; u<2304; u+=256){
    float v = 0.f;
    #pragma unroll
    for (int m=0;m<32;m++) v += base[(size_t)m*2304 + u];
    sm[u] = v;
  }
  if (tid < 48){
    const float* bk = pks + (size_t)bh*32*48 + tid;
    float v = 0.f;
    #pragma unroll
    for (int m=0;m<32;m++) v += bk[m*48];
    ks[tid] = v;
  }
  __syncthreads();
  for (int u=tid; u<4096; u+=256){
    int e = u >> 6, d = u & 63;
    float v = 0.f;
    if (e < 48 && d < 48)       v = sm[d*48 + e];
    else if (e == 48 && d < 48) v = ks[d];
    kvp[((size_t)bh*64 + e)*64 + d] = f2bf(v);
  }
}

// ---------------- k6: num/den -> ahh head-major [bh][n][48], coalesced ----
__global__ __launch_bounds__(256) void k6_num(
    const u16* __restrict__ qh, const u16* __restrict__ kvp, u16* __restrict__ ahh)
{
  __shared__ __align__(16) u16 As[256*64]; // 32KB; reused as [256][48] ahat staging
  __shared__ __align__(16) u16 Bs[64*64];  // 8KB
  const int bh = blockIdx.x >> 4, nc = blockIdx.x & 15;
  const int tid = threadIdx.x, w = tid>>6, l = tid&63;
  const int lc = l & 15, hi = l >> 4;
  const f32x4 zf = {0.f,0.f,0.f,0.f};
  const uint4 z4 = {0,0,0,0};
  const u16* gq = qh + ((size_t)bh*4096 + nc*256)*48;
  #pragma unroll
  for (int it=0; it<8; ++it){
    int s = it*256 + tid;
    int row = s>>3, c = s&7, g = c ^ (row&7);
    ((uint4*)As)[s] = (g < 6) ? *(const uint4*)(gq + (size_t)row*48 + g*8) : z4;
  }
  const u16* gk = kvp + (size_t)bh*4096;
  #pragma unroll
  for (int it=0; it<2; ++it){
    int s = it*256 + tid;
    int row = s>>3, c = s&7, g = c ^ (row&7);
    ((uint4*)Bs)[s] = *(const uint4*)(gk + (size_t)row*64 + g*8);
  }
  __syncthreads();
  f32x4 acc[4][4];
  #pragma unroll
  for (int i=0;i<4;i++)
    #pragma unroll
    for (int j=0;j<4;j++) acc[i][j] = zf;
  const int rbase = w*64;
  #pragma unroll
  for (int kk=0; kk<64; kk+=32){
    const int sc = (((kk>>3)+hi) ^ (lc&7))*8;
    bf16x8 a[4], bb[4];
    #pragma unroll
    for (int i=0;i<4;i++) a[i]  = *(const bf16x8*)&As[(rbase + i*16 + lc)*64 + sc];
    #pragma unroll
    for (int j=0;j<4;j++) bb[j] = *(const bf16x8*)&Bs[(j*16 + lc)*64 + sc];
    #pragma unroll
    for (int i=0;i<4;i++)
      #pragma unroll
      for (int j=0;j<4;j++)
        acc[i][j] = MFMA16(a[i], bb[j], acc[i][j]);
  }
  __syncthreads();   // all As reads done; reuse As as [256][48] staging
  #pragma unroll
  for (int i=0;i<4;i++){
    #pragma unroll
    for (int r=0;r<4;r++){
      float den = __shfl(acc[i][3][r], l & 48, 64) + EPSF;
      float rd = __builtin_amdgcn_rcpf(den);
      int row = rbase + i*16 + hi*4 + r;
      As[row*48 +      lc] = f2bf(acc[i][0][r]*rd);
      As[row*48 + 16 + lc] = f2bf(acc[i][1][r]*rd);
      As[row*48 + 32 + lc] = f2bf(acc[i][2][r]*rd);
    }
  }
  __syncthreads();
  // linear coalesced store: 256*48 u16 = 1536 uint4, 6 per thread
  size_t gab = ((size_t)bh*4096 + nc*256)*48;
  #pragma unroll
  for (int it=0; it<6; ++it){
    int s = it*256 + tid;
    *(uint4*)(ahh + gab + (size_t)s*8) = *(const uint4*)&As[s*8];
  }
}

// ---------------- k7: out = ahh @ wo^T + bo (fp32); head-major A gather ---
__global__ __launch_bounds__(256) void k7_gemm_out(
    const u16* __restrict__ ahh, const u16* __restrict__ wob,
    const float* __restrict__ bo, float* __restrict__ out)
{
  __shared__ __align__(16) u16 smem[32768];  // 64KB dbuf
  const int m0 = blockIdx.x * 128;
  const int n0 = blockIdx.y * 128;
  const int tid = threadIdx.x, w = tid>>6, l = tid&63;
  const int lc = l & 15, hi = l >> 4;
  const int sw  = (l&7) ^ (l>>3);
  const int osw = sw*16;
  const f32x4 zf = {0.f,0.f,0.f,0.f};
  f32x4 acc[4][4];
  #pragma unroll
  for (int i=0;i<4;i++)
    #pragma unroll
    for (int j=0;j<4;j++) acc[i][j] = zf;

  const int srow = (w*4)*8 + (l>>3);

  // A source: ahh[bh][n][48]; chunk cg (0..47) -> head cg/6, sub-chunk cg%6
  #define K7_STAGE(T, BUF) do {                                              \
    const int k0_ = (T)*64;                                                  \
    const int cg_ = k0_/8 + sw;                                              \
    const int h_  = cg_/6, cc_ = cg_ - h_*6;                                 \
    char* Ab_ = (char*)(smem + (BUF)*8192);                                  \
    char* Bb_ = (char*)(smem + 16384 + (BUF)*8192);                          \
    _Pragma("unroll")                                                        \
    for (int i=0;i<4;i++){                                                   \
      int m_ = m0 + srow + i*8;                                              \
      gll16((const char*)ahh +                                               \
            ((((size_t)(m_>>12)*8 + h_)*4096 + (m_&4095))*48 + cc_*8)*2,     \
            Ab_ + (w*4+i)*1024);                                             \
      gll16((const char*)wob + ((size_t)(n0+srow+i*8)*384 + k0_)*2 + osw,    \
            Bb_ + (w*4+i)*1024);                                             \
    }                                                                        \
  } while(0)

  K7_STAGE(0, 0);
  __syncthreads();
  int cur = 0;
  for (int t_=0; t_<6; ++t_){
    if (t_ < 5) K7_STAGE(t_+1, cur^1);
    const u16* As = smem + cur*8192;
    const u16* Bs = smem + 16384 + cur*8192;
    const int wr = (w>>1)*64, wc = (w&1)*64;
    #pragma unroll
    for (int kk=0; kk<64; kk+=32){
      const int sc = (((kk>>3)+hi) ^ (lc&7))*8;
      bf16x8 a[4], bb[4];
      #pragma unroll
      for (int i=0;i<4;i++) a[i]  = *(const bf16x8*)&As[(wr + i*16 + lc)*64 + sc];
      #pragma unroll
      for (int j=0;j<4;j++) bb[j] = *(const bf16x8*)&Bs[(wc + j*16 + lc)*64 + sc];
      #pragma unroll
      for (int i=0;i<4;i++)
        #pragma unroll
        for (int j=0;j<4;j++)
          acc[i][j] = MFMA16(a[i], bb[j], acc[i][j]);
    }
    __syncthreads();
    cur ^= 1;
  }
  #undef K7_STAGE
  const int wr=(w>>1)*64, wc=(w&1)*64;
  #pragma unroll
  for (int j=0;j<4;j++){
    int n = n0 + wc + j*16 + lc;
    float bias = bo[n];
    #pragma unroll
    for (int i=0;i<4;i++)
      #pragma unroll
      for (int r=0;r<4;r++){
        int m = m0 + wr + i*16 + hi*4 + r;
        out[(size_t)m*384 + n] = acc[i][j][r] + bias;
      }
  }
}

extern "C" void kernel_launch(void* const* d_in, const int* in_sizes, int n_in,
                              void* d_out, int out_size, void* d_ws, size_t ws_size,
                              hipStream_t stream)
{
  const float* x    = (const float*)d_in[0];
  const float* wq   = (const float*)d_in[1];
  const float* bq   = (const float*)d_in[2];
  const float* wk   = (const float*)d_in[3];
  const float* bk   = (const float*)d_in[4];
  const float* wv   = (const float*)d_in[5];
  const float* bv   = (const float*)d_in[6];
  const float* wg   = (const float*)d_in[7];
  const float* bg   = (const float*)d_in[8];
  const float* wo   = (const float*)d_in[9];
  const float* bo   = (const float*)d_in[10];
  const float* temp = (const float*)d_in[11];
  const float* dw_w = (const float*)d_in[12];
  const float* dw_b = (const float*)d_in[13];
  const float* pw_w = (const float*)d_in[14];
  const float* pw_b = (const float*)d_in[15];
  float* out = (float*)d_out;
  char* ws = (char*)d_ws;

  u16*   t       = (u16*)(ws + 0);
  float* pkv     = (float*)(ws + 0);          // 18874368  [64][32][2304] f32
  float* pks     = (float*)(ws + 18874368);   // 393216    [64][32][48] f32
  u16*   ahh     = (u16*)(ws + 0);            // 25165824  [bh][n][48] (k6 out)
  u16*   xm      = (u16*)(ws + 25165824);     // 25165824
  u16*   qh      = (u16*)(ws + 50331648);     // 25165824  [bh][n][48]
  u16*   wpack   = (u16*)(ws + 83886080);     // 1179648
  u16*   pwb     = (u16*)(ws + 85065728);     // 294912
  u16*   wob     = (u16*)(ws + 85360640);     // 294912
  float* bpack   = (float*)(ws + 85655552);   // 6144
  u16*   kvp     = (u16*)(ws + 85661696);     // 524288  [64][64][64] bf16

  k01_prep_dw<<<6528, 256, 0, stream>>>(wq,bq,wk,bk,wv,bv,wg,bg,pw_w,wo,
                                        wpack,pwb,wob,bpack,
                                        x, dw_w, dw_b, t);
  k2_gemm_pw<<<dim3(256,3), 256, 0, stream>>>(t, pwb, x, pw_b, xm);
  k3_gemm_qkvg<<<dim3(256,8), 256, 0, stream>>>(xm, wpack, bpack, temp, qh, pkv, pks);
  k5_red<<<64, 256, 0, stream>>>(pkv, pks, kvp);
  k6_num<<<1024, 256, 0, stream>>>(qh, kvp, ahh);
  k7_gemm_out<<<dim3(256,3), 256, 0, stream>>>(ahh, wob, bo, out);
}